// Round 8
// baseline (215.876 us; speedup 1.0000x reference)
//
#include <hip/hip_runtime.h>
#include <math.h>

static inline size_t ws_align(size_t x) { return (x + 255) & ~size_t(255); }

typedef float f32x4 __attribute__((ext_vector_type(4)));
typedef short bf16x8 __attribute__((ext_vector_type(8)));

__device__ inline unsigned int bf16rne(float f) {
    unsigned int u = __float_as_uint(f);
    u += 0x7FFFu + ((u >> 16) & 1u);
    return u >> 16;
}
__device__ inline float bf2f(unsigned int u) {  // low 16 bits = bf16
    return __uint_as_float(u << 16);
}
__device__ inline float bf2f_hi(unsigned int u) {  // high 16 bits
    return __uint_as_float(u & 0xFFFF0000u);
}

// ---------------- zero deg ----------------
__global__ void zero_kernel(int* __restrict__ p, int n) {
    int i = blockIdx.x * blockDim.x + threadIdx.x;
    if (i < n) p[i] = 0;
}

// ---------------- degree histogram + per-edge slot ----------------
__global__ void deg_pos_kernel(const int* __restrict__ dst, int E,
                               int* __restrict__ deg, int* __restrict__ pos) {
    int e = blockIdx.x * blockDim.x + threadIdx.x;
    if (e < E) pos[e] = atomicAdd(&deg[dst[e]], 1);
}

// ---------------- scan pass 1 (block sums) + dinv fused ----------------
__global__ void scan1_dinv_kernel(const int* __restrict__ deg, int* __restrict__ bsum,
                                  float* __restrict__ dinv, int n) {
    __shared__ int sdata[256];
    int base = blockIdx.x * 1024;
    int sum = 0;
    for (int i = threadIdx.x; i < 1024; i += 256) {
        int idx = base + i;
        if (idx < n) {
            int d = deg[idx];
            sum += d;
            dinv[idx] = rsqrtf((float)(d + 1));  // +1 self-loop
        }
    }
    sdata[threadIdx.x] = sum;
    __syncthreads();
    for (int s = 128; s > 0; s >>= 1) {
        if (threadIdx.x < s) sdata[threadIdx.x] += sdata[threadIdx.x + s];
        __syncthreads();
    }
    if (threadIdx.x == 0) bsum[blockIdx.x] = sdata[0];
}

// ---------------- W -> MFMA B-fragment layout (device body) ------------------
template <int FOUT, int CT>
__device__ void wconv_body(const float* __restrict__ W, unsigned short* __restrict__ wf) {
    for (int idx = threadIdx.x; idx < CT * 2 * 64 * 8; idx += 256) {
        int j = idx & 7;
        int lane = (idx >> 3) & 63;
        int kh = (idx >> 9) & 1;
        int ct = idx >> 10;
        int k = kh * 32 + ((lane >> 4) * 8) + j;
        int col = ct * 16 + (lane & 15);
        float v = (col < FOUT) ? W[k * FOUT + col] : 0.0f;
        wf[idx] = (unsigned short)bf16rne(v);
    }
}

// ---------------- scan pass 2 (1 block) + wconv x3 (blocks 1..3) -------------
__global__ void scan2_wconv_kernel(int* __restrict__ bsum, int nb,
                                   const float* __restrict__ W0, const float* __restrict__ W1,
                                   const float* __restrict__ W2,
                                   unsigned short* __restrict__ wf0, unsigned short* __restrict__ wf1,
                                   unsigned short* __restrict__ wf2) {
    if (blockIdx.x == 1) { wconv_body<64, 4>(W0, wf0); return; }
    if (blockIdx.x == 2) { wconv_body<64, 4>(W1, wf1); return; }
    if (blockIdx.x == 3) { wconv_body<40, 3>(W2, wf2); return; }
    __shared__ int sdata[256];
    int v = (threadIdx.x < nb) ? bsum[threadIdx.x] : 0;
    sdata[threadIdx.x] = v;
    __syncthreads();
    for (int off = 1; off < 256; off <<= 1) {
        int t = (threadIdx.x >= off) ? sdata[threadIdx.x - off] : 0;
        __syncthreads();
        sdata[threadIdx.x] += t;
        __syncthreads();
    }
    if (threadIdx.x < nb) bsum[threadIdx.x] = sdata[threadIdx.x] - v;  // exclusive
}

__global__ void scan3_kernel(const int* __restrict__ deg, const int* __restrict__ bsum,
                             int* __restrict__ rowptr, int n) {
    __shared__ int ssum[256];
    int base = blockIdx.x * 1024 + threadIdx.x * 4;
    int v[4];
    int s = 0;
#pragma unroll
    for (int k = 0; k < 4; ++k) {
        int idx = base + k;
        v[k] = (idx < n) ? deg[idx] : 0;
        s += v[k];
    }
    ssum[threadIdx.x] = s;
    __syncthreads();
    for (int off = 1; off < 256; off <<= 1) {
        int t = (threadIdx.x >= off) ? ssum[threadIdx.x - off] : 0;
        __syncthreads();
        ssum[threadIdx.x] += t;
        __syncthreads();
    }
    int ex = (threadIdx.x > 0 ? ssum[threadIdx.x - 1] : 0) + bsum[blockIdx.x];
#pragma unroll
    for (int k = 0; k < 4; ++k) {
        int idx = base + k;
        if (idx < n) rowptr[idx] = ex;
        ex += v[k];
    }
}

// ---------------- CSR fill (no atomic, adj only) -----------------------------
__global__ void fill_kernel(const int* __restrict__ src, const int* __restrict__ dst,
                            const int* __restrict__ pos, const int* __restrict__ rowptr,
                            int* __restrict__ adj, int E) {
    int e = blockIdx.x * blockDim.x + threadIdx.x;
    if (e >= E) return;
    adj[rowptr[dst[e]] + pos[e]] = src[e];
}

// ---------------- MFMA dense transform -> hs = dinv * (in @ W), bf16 --------
// FIN fixed at 64. IN_MODE: 0 = fp32 unsplit rows; 1 = bf16 split planes.
// OUT_MODE: 1 = split planes [2][n][32]; 0 = unsplit [n][FOUT].
template <int FOUT, int CT, int IN_MODE, int OUT_MODE, int MT>
__global__ void gemm_mfma_kernel(const void* __restrict__ in_, const unsigned short* __restrict__ wf,
                                 const float* __restrict__ dinv, unsigned int* __restrict__ hs32,
                                 int n) {
    int lane = threadIdx.x & 63;
    int tile0 = (blockIdx.x * 4 + (threadIdx.x >> 6)) * MT;
    if (tile0 * 16 >= n) return;
    bf16x8 bfrag[CT][2];
#pragma unroll
    for (int ct = 0; ct < CT; ++ct)
#pragma unroll
        for (int kh = 0; kh < 2; ++kh)
            bfrag[ct][kh] = *(const bf16x8*)(wf + ((size_t)(ct * 2 + kh) * 64 + lane) * 8);

    int rloc = lane & 15;   // A row within tile
    int koct = lane >> 4;   // k octet 0..3
    for (int t = 0; t < MT; ++t) {
        int rbase = (tile0 + t) * 16;
        if (rbase >= n) break;
        int r = rbase + rloc;
        int rc = (r < n) ? r : (n - 1);
        bf16x8 af0, af1;
        if (IN_MODE == 1) {
            const unsigned short* inb = (const unsigned short*)in_;
            af0 = *(const bf16x8*)(inb + (size_t)rc * 32 + koct * 8);                     // plane 0: k 0..31
            af1 = *(const bf16x8*)(inb + (size_t)n * 32 + (size_t)rc * 32 + koct * 8);    // plane 1: k 32..63
        } else {
            const float* inf = (const float*)in_;
            const float* ap = inf + (size_t)rc * 64 + koct * 8;
            float av[16];
            *(float4*)(av + 0)  = *(const float4*)(ap + 0);
            *(float4*)(av + 4)  = *(const float4*)(ap + 4);
            *(float4*)(av + 8)  = *(const float4*)(ap + 32);
            *(float4*)(av + 12) = *(const float4*)(ap + 36);
#pragma unroll
            for (int j = 0; j < 8; ++j) {
                af0[j] = (short)bf16rne(av[j]);
                af1[j] = (short)bf16rne(av[8 + j]);
            }
        }
#pragma unroll
        for (int ct = 0; ct < CT; ++ct) {
            f32x4 acc = {0.0f, 0.0f, 0.0f, 0.0f};
            acc = __builtin_amdgcn_mfma_f32_16x16x32_bf16(af0, bfrag[ct][0], acc, 0, 0, 0);
            acc = __builtin_amdgcn_mfma_f32_16x16x32_bf16(af1, bfrag[ct][1], acc, 0, 0, 0);
            int col = ct * 16 + rloc;  // D col = lane&15
#pragma unroll
            for (int reg = 0; reg < 4; ++reg) {
                int row = rbase + koct * 4 + reg;  // D row = (lane>>4)*4+reg
                float dd = dinv[(row < n) ? row : (n - 1)];
                float v = acc[reg] * dd;
                float po = __shfl_xor(v, 1, 64);   // partner column (lane^1)
                if (row < n && ((lane & 1) == 0) && col < FOUT) {
                    unsigned int packed = bf16rne(v) | (bf16rne(po) << 16);
                    if (OUT_MODE == 1) {
                        int plane = col >> 5, colp = col & 31;
                        hs32[(size_t)plane * n * 16 + (size_t)row * 16 + (colp >> 1)] = packed;
                    } else {
                        hs32[((size_t)row * FOUT + col) >> 1] = packed;
                    }
                }
            }
        }
    }
}

// ---------------- gather half-pass: one 3.2MB plane (L2-resident) ------------
// 16-lane quarter per node; lane i handles features {2i, 2i+1} of this half.
// t = dinv[v]*(hs[v] + sum hs[src]) + b ; store bf16(relu(t)) to out plane.
__global__ void gather_half_kernel(const int* __restrict__ rowptr, const int* __restrict__ deg,
                                   const int* __restrict__ adj, const unsigned int* __restrict__ hplane,
                                   const float* __restrict__ dinv, const float* __restrict__ b,
                                   unsigned int* __restrict__ outplane, int n) {
    int lane = threadIdx.x & 63;
    int wid = threadIdx.x >> 6;
    int q = lane >> 4;
    int i = lane & 15;
    int node = blockIdx.x * 16 + wid * 4 + q;
    if (node >= n) return;
    unsigned int hv = hplane[(size_t)node * 16 + i];  // self term
    float ax = bf2f(hv), ay = bf2f_hi(hv);
    int r0 = rowptr[node];
    int cnt = deg[node];
    int nf = cnt & ~15;
    for (int j0 = 0; j0 < nf; j0 += 16) {
#pragma unroll
        for (int t = 0; t < 16; ++t) {
            int s = adj[r0 + j0 + t];            // quarter-uniform broadcast
            unsigned int v = hplane[(size_t)s * 16 + i];
            ax += bf2f(v);
            ay += bf2f_hi(v);
        }
    }
#pragma unroll
    for (int t = 0; t < 16; ++t) {
        int idx = nf + t;
        if (idx < cnt) {
            int s = adj[r0 + idx];
            unsigned int v = hplane[(size_t)s * 16 + i];
            ax += bf2f(v);
            ay += bf2f_hi(v);
        }
    }
    float dd = dinv[node];
    float tx = fmaf(ax, dd, b[2 * i]);
    float ty = fmaf(ay, dd, b[2 * i + 1]);
    unsigned int o = bf16rne(fmaxf(tx, 0.0f)) | (bf16rne(fmaxf(ty, 0.0f)) << 16);
    outplane[(size_t)node * 16 + i] = o;
}

// ---------------- final gather (F=40) + fused log_softmax --------------------
template <int F>  // F % 4 == 0
__global__ void gather_lsm_kernel(const int* __restrict__ rowptr, const int* __restrict__ deg,
                                  const int* __restrict__ adj, const unsigned short* __restrict__ hs,
                                  const float* __restrict__ dinv, const float* __restrict__ b,
                                  float* __restrict__ outp, int n) {
    const int F4 = F / 4;
    int lane = threadIdx.x & 63;
    int wid = threadIdx.x >> 6;
    int q = lane >> 4;
    int i = lane & 15;
    int node = blockIdx.x * 16 + wid * 4 + q;
    if (node >= n) return;
    const bool fv = (i < F4);
    const ushort4* h4 = (const ushort4*)hs;
    float4 acc = make_float4(0.f, 0.f, 0.f, 0.f);
    if (fv) {
        ushort4 hv = h4[(size_t)node * F4 + i];   // self term
        acc.x = bf2f(hv.x); acc.y = bf2f(hv.y); acc.z = bf2f(hv.z); acc.w = bf2f(hv.w);
    }
    int r0 = rowptr[node];
    int cnt = deg[node];
    int nf = cnt & ~15;
    for (int j0 = 0; j0 < nf; j0 += 16) {
#pragma unroll
        for (int t = 0; t < 16; ++t) {
            int s = adj[r0 + j0 + t];
            if (fv) {
                ushort4 hv = h4[(size_t)s * F4 + i];
                acc.x += bf2f(hv.x); acc.y += bf2f(hv.y);
                acc.z += bf2f(hv.z); acc.w += bf2f(hv.w);
            }
        }
    }
#pragma unroll
    for (int t = 0; t < 16; ++t) {
        int idx = nf + t;
        if (idx < cnt) {
            int s = adj[r0 + idx];
            if (fv) {
                ushort4 hv = h4[(size_t)s * F4 + i];
                acc.x += bf2f(hv.x); acc.y += bf2f(hv.y);
                acc.z += bf2f(hv.z); acc.w += bf2f(hv.w);
            }
        }
    }
    float dd = dinv[node];
    float4 tv = make_float4(-INFINITY, -INFINITY, -INFINITY, -INFINITY);
    if (fv) {
        float4 bv = ((const float4*)b)[i];
        tv.x = fmaf(acc.x, dd, bv.x);
        tv.y = fmaf(acc.y, dd, bv.y);
        tv.z = fmaf(acc.z, dd, bv.z);
        tv.w = fmaf(acc.w, dd, bv.w);
    }
    // log-softmax over the quarter's F values (width-16 reduction)
    float m = fmaxf(fmaxf(tv.x, tv.y), fmaxf(tv.z, tv.w));
#pragma unroll
    for (int off = 8; off >= 1; off >>= 1) m = fmaxf(m, __shfl_xor(m, off, 16));
    float es = fv ? (expf(tv.x - m) + expf(tv.y - m) + expf(tv.z - m) + expf(tv.w - m)) : 0.0f;
#pragma unroll
    for (int off = 8; off >= 1; off >>= 1) es += __shfl_xor(es, off, 16);
    float ls = logf(es);
    if (fv) {
        float4 o = make_float4(tv.x - m - ls, tv.y - m - ls, tv.z - m - ls, tv.w - m - ls);
        ((float4*)outp)[(size_t)node * F4 + i] = o;
    }
}

extern "C" void kernel_launch(void* const* d_in, const int* in_sizes, int n_in,
                              void* d_out, int out_size, void* d_ws, size_t ws_size,
                              hipStream_t stream) {
    const float* x  = (const float*)d_in[0];
    const int*   ei = (const int*)d_in[1];
    const float* W0 = (const float*)d_in[2];
    const float* b0 = (const float*)d_in[3];
    const float* W1 = (const float*)d_in[4];
    const float* b1 = (const float*)d_in[5];
    const float* W2 = (const float*)d_in[6];
    const float* b2 = (const float*)d_in[7];
    float* out = (float*)d_out;

    const int H   = in_sizes[3];            // 64
    const int FIN = in_sizes[2] / H;        // 64
    const int n   = in_sizes[0] / FIN;      // 50000
    const int E   = in_sizes[1] / 2;        // 800000
    (void)FIN;

    const int* srcp = ei;
    const int* dstp = ei + E;

    char* ws = (char*)d_ws;
    size_t off = 0;
    int*   deg    = (int*)(ws + off);   off += ws_align((size_t)n * 4);
    int*   rowptr = (int*)(ws + off);   off += ws_align((size_t)n * 4);
    int*   bsum   = (int*)(ws + off);   off += ws_align(256 * 4);
    float* dinv   = (float*)(ws + off); off += ws_align((size_t)n * 4);
    int*   pos    = (int*)(ws + off);   off += ws_align((size_t)E * 4);
    int*   adj    = (int*)(ws + off);   off += ws_align((size_t)E * 4);
    unsigned int* hs   = (unsigned int*)(ws + off); off += ws_align((size_t)n * H * 2);  // 2 planes of n*16 u32
    unsigned int* actB = (unsigned int*)(ws + off); off += ws_align((size_t)n * H * 2);  // 2 planes of n*16 u32
    unsigned short* wf0 = (unsigned short*)(ws + off); off += ws_align(4 * 2 * 64 * 8 * 2);
    unsigned short* wf1 = (unsigned short*)(ws + off); off += ws_align(4 * 2 * 64 * 8 * 2);
    unsigned short* wf2 = (unsigned short*)(ws + off); off += ws_align(3 * 2 * 64 * 8 * 2);

    // CSR build (deg zeroed by kernel; pos needs no init)
    zero_kernel<<<(n + 255) / 256, 256, 0, stream>>>(deg, n);
    deg_pos_kernel<<<(E + 255) / 256, 256, 0, stream>>>(dstp, E, deg, pos);
    int nscan = (n + 1023) / 1024;  // 49
    scan1_dinv_kernel<<<nscan, 256, 0, stream>>>(deg, bsum, dinv, n);
    scan2_wconv_kernel<<<4, 256, 0, stream>>>(bsum, nscan, W0, W1, W2, wf0, wf1, wf2);
    scan3_kernel<<<nscan, 256, 0, stream>>>(deg, bsum, rowptr, n);
    fill_kernel<<<(E + 255) / 256, 256, 0, stream>>>(srcp, dstp, pos, rowptr, adj, E);

    const int MT = 2;  // row-tiles per wave
    int tiles = (n + 15) / 16;                        // 3125
    int gemm_grid = (tiles + 4 * MT - 1) / (4 * MT);  // 391
    int node_grid = (n + 15) / 16;                    // 16 nodes/block
    size_t pl = (size_t)n * 16;                       // plane stride in u32

    // layer 0: x fp32 -> hs planes ; gather halves -> actB planes (relu bf16)
    gemm_mfma_kernel<64, 4, 0, 1, MT><<<gemm_grid, 256, 0, stream>>>(x, wf0, dinv, hs, n);
    gather_half_kernel<<<node_grid, 256, 0, stream>>>(rowptr, deg, adj, hs,      dinv, b0,      actB,      n);
    gather_half_kernel<<<node_grid, 256, 0, stream>>>(rowptr, deg, adj, hs + pl, dinv, b0 + 32, actB + pl, n);
    // layer 1
    gemm_mfma_kernel<64, 4, 1, 1, MT><<<gemm_grid, 256, 0, stream>>>(actB, wf1, dinv, hs, n);
    gather_half_kernel<<<node_grid, 256, 0, stream>>>(rowptr, deg, adj, hs,      dinv, b1,      actB,      n);
    gather_half_kernel<<<node_grid, 256, 0, stream>>>(rowptr, deg, adj, hs + pl, dinv, b1 + 32, actB + pl, n);
    // layer 2: gemm -> hs (n x 40 unsplit) ; gather + fused log_softmax -> out
    gemm_mfma_kernel<40, 3, 1, 0, MT><<<gemm_grid, 256, 0, stream>>>(actB, wf2, dinv, hs, n);
    gather_lsm_kernel<40><<<node_grid, 256, 0, stream>>>(rowptr, deg, adj, (const unsigned short*)hs, dinv, b2, out, n);
}

// Round 9
// 215.787 us; speedup vs baseline: 1.0004x; 1.0004x over previous
//
#include <hip/hip_runtime.h>
#include <math.h>

static inline size_t ws_align(size_t x) { return (x + 255) & ~size_t(255); }

typedef float f32x4 __attribute__((ext_vector_type(4)));
typedef short bf16x8 __attribute__((ext_vector_type(8)));

__device__ inline unsigned int bf16rne(float f) {
    unsigned int u = __float_as_uint(f);
    u += 0x7FFFu + ((u >> 16) & 1u);
    return u >> 16;
}
__device__ inline float bf2f(unsigned int u) {  // low 16 bits = bf16
    return __uint_as_float(u << 16);
}
__device__ inline float bf2f_hi(unsigned int u) {  // high 16 bits
    return __uint_as_float(u & 0xFFFF0000u);
}

// ---------------- zero deg ----------------
__global__ void zero_kernel(int* __restrict__ p, int n) {
    int i = blockIdx.x * blockDim.x + threadIdx.x;
    if (i < n) p[i] = 0;
}

// ---------------- degree histogram + per-edge slot ----------------
__global__ void deg_pos_kernel(const int* __restrict__ dst, int E,
                               int* __restrict__ deg, int* __restrict__ pos) {
    int e = blockIdx.x * blockDim.x + threadIdx.x;
    if (e < E) pos[e] = atomicAdd(&deg[dst[e]], 1);
}

// ---------------- scan pass 1 (block sums) + dinv fused ----------------
__global__ void scan1_dinv_kernel(const int* __restrict__ deg, int* __restrict__ bsum,
                                  float* __restrict__ dinv, int n) {
    __shared__ int sdata[256];
    int base = blockIdx.x * 1024;
    int sum = 0;
    for (int i = threadIdx.x; i < 1024; i += 256) {
        int idx = base + i;
        if (idx < n) {
            int d = deg[idx];
            sum += d;
            dinv[idx] = rsqrtf((float)(d + 1));  // +1 self-loop
        }
    }
    sdata[threadIdx.x] = sum;
    __syncthreads();
    for (int s = 128; s > 0; s >>= 1) {
        if (threadIdx.x < s) sdata[threadIdx.x] += sdata[threadIdx.x + s];
        __syncthreads();
    }
    if (threadIdx.x == 0) bsum[blockIdx.x] = sdata[0];
}

// ---------------- W -> MFMA B-fragment layout (device body) ------------------
template <int FOUT, int CT>
__device__ void wconv_body(const float* __restrict__ W, unsigned short* __restrict__ wf) {
    for (int idx = threadIdx.x; idx < CT * 2 * 64 * 8; idx += 256) {
        int j = idx & 7;
        int lane = (idx >> 3) & 63;
        int kh = (idx >> 9) & 1;
        int ct = idx >> 10;
        int k = kh * 32 + ((lane >> 4) * 8) + j;
        int col = ct * 16 + (lane & 15);
        float v = (col < FOUT) ? W[k * FOUT + col] : 0.0f;
        wf[idx] = (unsigned short)bf16rne(v);
    }
}

// ---------------- scan pass 2 (1 block) + wconv x3 (blocks 1..3) -------------
__global__ void scan2_wconv_kernel(int* __restrict__ bsum, int nb,
                                   const float* __restrict__ W0, const float* __restrict__ W1,
                                   const float* __restrict__ W2,
                                   unsigned short* __restrict__ wf0, unsigned short* __restrict__ wf1,
                                   unsigned short* __restrict__ wf2) {
    if (blockIdx.x == 1) { wconv_body<64, 4>(W0, wf0); return; }
    if (blockIdx.x == 2) { wconv_body<64, 4>(W1, wf1); return; }
    if (blockIdx.x == 3) { wconv_body<40, 3>(W2, wf2); return; }
    __shared__ int sdata[256];
    int v = (threadIdx.x < nb) ? bsum[threadIdx.x] : 0;
    sdata[threadIdx.x] = v;
    __syncthreads();
    for (int off = 1; off < 256; off <<= 1) {
        int t = (threadIdx.x >= off) ? sdata[threadIdx.x - off] : 0;
        __syncthreads();
        sdata[threadIdx.x] += t;
        __syncthreads();
    }
    if (threadIdx.x < nb) bsum[threadIdx.x] = sdata[threadIdx.x] - v;  // exclusive
}

__global__ void scan3_kernel(const int* __restrict__ deg, const int* __restrict__ bsum,
                             int* __restrict__ rowptr, int n) {
    __shared__ int ssum[256];
    int base = blockIdx.x * 1024 + threadIdx.x * 4;
    int v[4];
    int s = 0;
#pragma unroll
    for (int k = 0; k < 4; ++k) {
        int idx = base + k;
        v[k] = (idx < n) ? deg[idx] : 0;
        s += v[k];
    }
    ssum[threadIdx.x] = s;
    __syncthreads();
    for (int off = 1; off < 256; off <<= 1) {
        int t = (threadIdx.x >= off) ? ssum[threadIdx.x - off] : 0;
        __syncthreads();
        ssum[threadIdx.x] += t;
        __syncthreads();
    }
    int ex = (threadIdx.x > 0 ? ssum[threadIdx.x - 1] : 0) + bsum[blockIdx.x];
#pragma unroll
    for (int k = 0; k < 4; ++k) {
        int idx = base + k;
        if (idx < n) rowptr[idx] = ex;
        ex += v[k];
    }
}

// ---------------- CSR fill (no atomic, adj only) -----------------------------
__global__ void fill_kernel(const int* __restrict__ src, const int* __restrict__ dst,
                            const int* __restrict__ pos, const int* __restrict__ rowptr,
                            int* __restrict__ adj, int E) {
    int e = blockIdx.x * blockDim.x + threadIdx.x;
    if (e >= E) return;
    adj[rowptr[dst[e]] + pos[e]] = src[e];
}

// ---------------- MFMA dense transform -> hs = dinv * (in @ W), bf16 planes --
// FIN fixed at 64. IN_MODE: 0 = fp32 unsplit rows; 1 = bf16 split planes.
template <int FOUT, int CT, int IN_MODE, int MT>
__global__ void gemm_mfma_kernel(const void* __restrict__ in_, const unsigned short* __restrict__ wf,
                                 const float* __restrict__ dinv, unsigned int* __restrict__ hs32,
                                 int n) {
    int lane = threadIdx.x & 63;
    int tile0 = (blockIdx.x * 4 + (threadIdx.x >> 6)) * MT;
    if (tile0 * 16 >= n) return;
    bf16x8 bfrag[CT][2];
#pragma unroll
    for (int ct = 0; ct < CT; ++ct)
#pragma unroll
        for (int kh = 0; kh < 2; ++kh)
            bfrag[ct][kh] = *(const bf16x8*)(wf + ((size_t)(ct * 2 + kh) * 64 + lane) * 8);

    int rloc = lane & 15;   // A row within tile
    int koct = lane >> 4;   // k octet 0..3
    for (int t = 0; t < MT; ++t) {
        int rbase = (tile0 + t) * 16;
        if (rbase >= n) break;
        int r = rbase + rloc;
        int rc = (r < n) ? r : (n - 1);
        bf16x8 af0, af1;
        if (IN_MODE == 1) {
            const unsigned short* inb = (const unsigned short*)in_;
            af0 = *(const bf16x8*)(inb + (size_t)rc * 32 + koct * 8);                     // plane 0: k 0..31
            af1 = *(const bf16x8*)(inb + (size_t)n * 32 + (size_t)rc * 32 + koct * 8);    // plane 1: k 32..63
        } else {
            const float* inf = (const float*)in_;
            const float* ap = inf + (size_t)rc * 64 + koct * 8;
            float av[16];
            *(float4*)(av + 0)  = *(const float4*)(ap + 0);
            *(float4*)(av + 4)  = *(const float4*)(ap + 4);
            *(float4*)(av + 8)  = *(const float4*)(ap + 32);
            *(float4*)(av + 12) = *(const float4*)(ap + 36);
#pragma unroll
            for (int j = 0; j < 8; ++j) {
                af0[j] = (short)bf16rne(av[j]);
                af1[j] = (short)bf16rne(av[8 + j]);
            }
        }
#pragma unroll
        for (int ct = 0; ct < CT; ++ct) {
            f32x4 acc = {0.0f, 0.0f, 0.0f, 0.0f};
            acc = __builtin_amdgcn_mfma_f32_16x16x32_bf16(af0, bfrag[ct][0], acc, 0, 0, 0);
            acc = __builtin_amdgcn_mfma_f32_16x16x32_bf16(af1, bfrag[ct][1], acc, 0, 0, 0);
            int col = ct * 16 + rloc;  // D col = lane&15
#pragma unroll
            for (int reg = 0; reg < 4; ++reg) {
                int row = rbase + koct * 4 + reg;  // D row = (lane>>4)*4+reg
                float dd = dinv[(row < n) ? row : (n - 1)];
                float v = acc[reg] * dd;
                float po = __shfl_xor(v, 1, 64);   // partner column (lane^1)
                if (row < n && ((lane & 1) == 0) && col < FOUT) {
                    unsigned int packed = bf16rne(v) | (bf16rne(po) << 16);
                    int plane = col >> 5, colp = col & 31;
                    hs32[(size_t)plane * n * 16 + (size_t)row * 16 + (colp >> 1)] = packed;
                }
            }
        }
    }
}

// ---------------- gather half-pass on one 3.2MB plane ------------------------
// 16-lane quarter per node; lane i handles features {2i, 2i+1}.
// sum = hs[v] + sum_{e: dst=v} hs[src_e]
// OMODE 0: outA = bf16(relu(dinv[v]*sum + b))
// OMODE 1: same + outB = bf16(dinv[v] * relu(...))   (pre-scaled for next agg)
// OMODE 2: outA = bf16(sum)                           (raw; scale folded later)
template <int OMODE, int TAG>
__global__ void gather_half_kernel(const int* __restrict__ rowptr, const int* __restrict__ deg,
                                   const int* __restrict__ adj, const unsigned int* __restrict__ hplane,
                                   const float* __restrict__ dinv, const float* __restrict__ b,
                                   unsigned int* __restrict__ outA, unsigned int* __restrict__ outB,
                                   int n) {
    int lane = threadIdx.x & 63;
    int wid = threadIdx.x >> 6;
    int q = lane >> 4;
    int i = lane & 15;
    int node = blockIdx.x * 16 + wid * 4 + q;
    if (node >= n) return;
    unsigned int hv = hplane[(size_t)node * 16 + i];  // self term
    float ax = bf2f(hv), ay = bf2f_hi(hv);
    int r0 = rowptr[node];
    int cnt = deg[node];
    int nf = cnt & ~15;
    for (int j0 = 0; j0 < nf; j0 += 16) {
#pragma unroll
        for (int t = 0; t < 16; ++t) {
            int s = adj[r0 + j0 + t];            // quarter-uniform broadcast
            unsigned int v = hplane[(size_t)s * 16 + i];
            ax += bf2f(v);
            ay += bf2f_hi(v);
        }
    }
#pragma unroll
    for (int t = 0; t < 16; ++t) {
        int idx = nf + t;
        if (idx < cnt) {
            int s = adj[r0 + idx];
            unsigned int v = hplane[(size_t)s * 16 + i];
            ax += bf2f(v);
            ay += bf2f_hi(v);
        }
    }
    if (OMODE == 2) {
        outA[(size_t)node * 16 + i] = bf16rne(ax) | (bf16rne(ay) << 16);
    } else {
        float dd = dinv[node];
        float tx = fmaxf(fmaf(ax, dd, b[2 * i]), 0.0f);
        float ty = fmaxf(fmaf(ay, dd, b[2 * i + 1]), 0.0f);
        outA[(size_t)node * 16 + i] = bf16rne(tx) | (bf16rne(ty) << 16);
        if (OMODE == 1) {
            outB[(size_t)node * 16 + i] = bf16rne(tx * dd) | (bf16rne(ty * dd) << 16);
        }
    }
}

// ---------------- final GEMM40 + dinv + bias + fused log_softmax -------------
// in = aggregated planes (bf16); out = log_softmax(dinv[row]*(agg@W2) + b2)
template <int MT>
__global__ void gemm40_lsm_kernel(const unsigned int* __restrict__ in_,
                                  const unsigned short* __restrict__ wf,
                                  const float* __restrict__ dinv, const float* __restrict__ b,
                                  float* __restrict__ out, int n) {
    const int CT = 3;
    int lane = threadIdx.x & 63;
    int tile0 = (blockIdx.x * 4 + (threadIdx.x >> 6)) * MT;
    if (tile0 * 16 >= n) return;
    bf16x8 bfrag[CT][2];
#pragma unroll
    for (int ct = 0; ct < CT; ++ct)
#pragma unroll
        for (int kh = 0; kh < 2; ++kh)
            bfrag[ct][kh] = *(const bf16x8*)(wf + ((size_t)(ct * 2 + kh) * 64 + lane) * 8);

    int rloc = lane & 15;
    int koct = lane >> 4;
    float bc[CT];
#pragma unroll
    for (int ct = 0; ct < CT; ++ct) {
        int col = ct * 16 + rloc;
        bc[ct] = (col < 40) ? b[col] : -INFINITY;
    }
    const unsigned short* inb = (const unsigned short*)in_;
    for (int t = 0; t < MT; ++t) {
        int rbase = (tile0 + t) * 16;
        if (rbase >= n) break;
        int r = rbase + rloc;
        int rc = (r < n) ? r : (n - 1);
        bf16x8 af0 = *(const bf16x8*)(inb + (size_t)rc * 32 + koct * 8);
        bf16x8 af1 = *(const bf16x8*)(inb + (size_t)n * 32 + (size_t)rc * 32 + koct * 8);
        f32x4 acc[CT];
#pragma unroll
        for (int ct = 0; ct < CT; ++ct) {
            f32x4 a = {0.0f, 0.0f, 0.0f, 0.0f};
            a = __builtin_amdgcn_mfma_f32_16x16x32_bf16(af0, bfrag[ct][0], a, 0, 0, 0);
            a = __builtin_amdgcn_mfma_f32_16x16x32_bf16(af1, bfrag[ct][1], a, 0, 0, 0);
            acc[ct] = a;
        }
#pragma unroll
        for (int reg = 0; reg < 4; ++reg) {
            int row = rbase + koct * 4 + reg;
            float dd = dinv[(row < n) ? row : (n - 1)];
            float v0 = fmaf(acc[0][reg], dd, bc[0]);
            float v1 = fmaf(acc[1][reg], dd, bc[1]);
            float v2 = fmaf(acc[2][reg], dd, bc[2]);
            float m = fmaxf(fmaxf(v0, v1), v2);
#pragma unroll
            for (int off = 8; off >= 1; off >>= 1) m = fmaxf(m, __shfl_xor(m, off, 16));
            float es = expf(v0 - m) + expf(v1 - m) + ((v2 == -INFINITY) ? 0.0f : expf(v2 - m));
#pragma unroll
            for (int off = 8; off >= 1; off >>= 1) es += __shfl_xor(es, off, 16);
            float ls = m + logf(es);
            if (row < n) {
                out[(size_t)row * 40 + rloc] = v0 - ls;
                out[(size_t)row * 40 + 16 + rloc] = v1 - ls;
                if (rloc < 8) out[(size_t)row * 40 + 32 + rloc] = v2 - ls;
            }
        }
    }
}

extern "C" void kernel_launch(void* const* d_in, const int* in_sizes, int n_in,
                              void* d_out, int out_size, void* d_ws, size_t ws_size,
                              hipStream_t stream) {
    const float* x  = (const float*)d_in[0];
    const int*   ei = (const int*)d_in[1];
    const float* W0 = (const float*)d_in[2];
    const float* b0 = (const float*)d_in[3];
    const float* W1 = (const float*)d_in[4];
    const float* b1 = (const float*)d_in[5];
    const float* W2 = (const float*)d_in[6];
    const float* b2 = (const float*)d_in[7];
    float* out = (float*)d_out;

    const int H   = in_sizes[3];            // 64
    const int FIN = in_sizes[2] / H;        // 64
    const int n   = in_sizes[0] / FIN;      // 50000
    const int E   = in_sizes[1] / 2;        // 800000
    (void)FIN;

    const int* srcp = ei;
    const int* dstp = ei + E;

    char* ws = (char*)d_ws;
    size_t off = 0;
    int*   deg    = (int*)(ws + off);   off += ws_align((size_t)n * 4);
    int*   rowptr = (int*)(ws + off);   off += ws_align((size_t)n * 4);
    int*   bsum   = (int*)(ws + off);   off += ws_align(256 * 4);
    float* dinv   = (float*)(ws + off); off += ws_align((size_t)n * 4);
    int*   pos    = (int*)(ws + off);   off += ws_align((size_t)E * 4);
    int*   adj    = (int*)(ws + off);   off += ws_align((size_t)E * 4);
    unsigned int* hs    = (unsigned int*)(ws + off); off += ws_align((size_t)n * H * 2);  // 2 planes n*16 u32
    unsigned int* actB  = (unsigned int*)(ws + off); off += ws_align((size_t)n * H * 2);
    unsigned int* actBs = (unsigned int*)(ws + off); off += ws_align((size_t)n * H * 2);
    unsigned short* wf0 = (unsigned short*)(ws + off); off += ws_align(4 * 2 * 64 * 8 * 2);
    unsigned short* wf1 = (unsigned short*)(ws + off); off += ws_align(4 * 2 * 64 * 8 * 2);
    unsigned short* wf2 = (unsigned short*)(ws + off); off += ws_align(3 * 2 * 64 * 8 * 2);

    // CSR build
    zero_kernel<<<(n + 255) / 256, 256, 0, stream>>>(deg, n);
    deg_pos_kernel<<<(E + 255) / 256, 256, 0, stream>>>(dstp, E, deg, pos);
    int nscan = (n + 1023) / 1024;  // 49
    scan1_dinv_kernel<<<nscan, 256, 0, stream>>>(deg, bsum, dinv, n);
    scan2_wconv_kernel<<<4, 256, 0, stream>>>(bsum, nscan, W0, W1, W2, wf0, wf1, wf2);
    scan3_kernel<<<nscan, 256, 0, stream>>>(deg, bsum, rowptr, n);
    fill_kernel<<<(E + 255) / 256, 256, 0, stream>>>(srcp, dstp, pos, rowptr, adj, E);

    const int MT = 2;
    int tiles = (n + 15) / 16;                        // 3125
    int gemm_grid = (tiles + 4 * MT - 1) / (4 * MT);  // 391
    int node_grid = (n + 15) / 16;                    // 16 nodes/block
    size_t pl = (size_t)n * 16;                       // plane stride (u32)

    // layer 0: gemm -> hs planes ; gather -> actB (relu bf16)
    gemm_mfma_kernel<64, 4, 0, MT><<<gemm_grid, 256, 0, stream>>>(x, wf0, dinv, hs, n);
    gather_half_kernel<0, 0><<<node_grid, 256, 0, stream>>>(rowptr, deg, adj, hs,      dinv, b0,      actB,      nullptr, n);
    gather_half_kernel<0, 1><<<node_grid, 256, 0, stream>>>(rowptr, deg, adj, hs + pl, dinv, b0 + 32, actB + pl, nullptr, n);
    // layer 1: gemm -> hs ; gather -> actB + actBs (dinv-prescaled)
    gemm_mfma_kernel<64, 4, 1, MT><<<gemm_grid, 256, 0, stream>>>(actB, wf1, dinv, hs, n);
    gather_half_kernel<1, 2><<<node_grid, 256, 0, stream>>>(rowptr, deg, adj, hs,      dinv, b1,      actB,      actBs,      n);
    gather_half_kernel<1, 3><<<node_grid, 256, 0, stream>>>(rowptr, deg, adj, hs + pl, dinv, b1 + 32, actB + pl, actBs + pl, n);
    // layer 2 (commuted): aggregate actBs -> hs (raw sums) ; gemm40 + lsm -> out
    gather_half_kernel<2, 4><<<node_grid, 256, 0, stream>>>(rowptr, deg, adj, actBs,      nullptr, nullptr, hs,      nullptr, n);
    gather_half_kernel<2, 5><<<node_grid, 256, 0, stream>>>(rowptr, deg, adj, actBs + pl, nullptr, nullptr, hs + pl, nullptr, n);
    gemm40_lsm_kernel<MT><<<gemm_grid, 256, 0, stream>>>(hs, wf2, dinv, b2, out, n);
}

// Round 11
// 177.506 us; speedup vs baseline: 1.2162x; 1.2157x over previous
//
#include <hip/hip_runtime.h>
#include <math.h>

static inline size_t ws_align(size_t x) { return (x + 255) & ~size_t(255); }

typedef float f32x4 __attribute__((ext_vector_type(4)));
typedef short bf16x8 __attribute__((ext_vector_type(8)));

__device__ inline unsigned int bf16rne(float f) {
    unsigned int u = __float_as_uint(f);
    u += 0x7FFFu + ((u >> 16) & 1u);
    return u >> 16;
}
__device__ inline float bf2f(unsigned int u) {  // low 16 bits = bf16
    return __uint_as_float(u << 16);
}
__device__ inline float bf2f_hi(unsigned int u) {  // high 16 bits
    return __uint_as_float(u & 0xFFFF0000u);
}

// ---------------- zero deg ----------------
__global__ void zero_kernel(int* __restrict__ p, int n) {
    int i = blockIdx.x * blockDim.x + threadIdx.x;
    if (i < n) p[i] = 0;
}

// ---------------- degree histogram + per-edge slot ----------------
__global__ void deg_pos_kernel(const int* __restrict__ dst, int E,
                               int* __restrict__ deg, int* __restrict__ pos) {
    int e = blockIdx.x * blockDim.x + threadIdx.x;
    if (e < E) pos[e] = atomicAdd(&deg[dst[e]], 1);
}

// ---------------- scan pass 1 (block sums) + dinv fused ----------------
__global__ void scan1_dinv_kernel(const int* __restrict__ deg, int* __restrict__ bsum,
                                  float* __restrict__ dinv, int n) {
    __shared__ int sdata[256];
    int base = blockIdx.x * 1024;
    int sum = 0;
    for (int i = threadIdx.x; i < 1024; i += 256) {
        int idx = base + i;
        if (idx < n) {
            int d = deg[idx];
            sum += d;
            dinv[idx] = rsqrtf((float)(d + 1));  // +1 self-loop
        }
    }
    sdata[threadIdx.x] = sum;
    __syncthreads();
    for (int s = 128; s > 0; s >>= 1) {
        if (threadIdx.x < s) sdata[threadIdx.x] += sdata[threadIdx.x + s];
        __syncthreads();
    }
    if (threadIdx.x == 0) bsum[blockIdx.x] = sdata[0];
}

// ---------------- W -> MFMA B-fragment layout (device body) ------------------
template <int FOUT, int CT>
__device__ void wconv_body(const float* __restrict__ W, unsigned short* __restrict__ wf) {
    for (int idx = threadIdx.x; idx < CT * 2 * 64 * 8; idx += 256) {
        int j = idx & 7;
        int lane = (idx >> 3) & 63;
        int kh = (idx >> 9) & 1;
        int ct = idx >> 10;
        int k = kh * 32 + ((lane >> 4) * 8) + j;
        int col = ct * 16 + (lane & 15);
        float v = (col < FOUT) ? W[k * FOUT + col] : 0.0f;
        wf[idx] = (unsigned short)bf16rne(v);
    }
}

// ---------------- scan pass 2 (1 block) + wconv x3 (blocks 1..3) -------------
__global__ void scan2_wconv_kernel(int* __restrict__ bsum, int nb,
                                   const float* __restrict__ W0, const float* __restrict__ W1,
                                   const float* __restrict__ W2,
                                   unsigned short* __restrict__ wf0, unsigned short* __restrict__ wf1,
                                   unsigned short* __restrict__ wf2) {
    if (blockIdx.x == 1) { wconv_body<64, 4>(W0, wf0); return; }
    if (blockIdx.x == 2) { wconv_body<64, 4>(W1, wf1); return; }
    if (blockIdx.x == 3) { wconv_body<40, 3>(W2, wf2); return; }
    __shared__ int sdata[256];
    int v = (threadIdx.x < nb) ? bsum[threadIdx.x] : 0;
    sdata[threadIdx.x] = v;
    __syncthreads();
    for (int off = 1; off < 256; off <<= 1) {
        int t = (threadIdx.x >= off) ? sdata[threadIdx.x - off] : 0;
        __syncthreads();
        sdata[threadIdx.x] += t;
        __syncthreads();
    }
    if (threadIdx.x < nb) bsum[threadIdx.x] = sdata[threadIdx.x] - v;  // exclusive
}

__global__ void scan3_kernel(const int* __restrict__ deg, const int* __restrict__ bsum,
                             int* __restrict__ rowptr, int n) {
    __shared__ int ssum[256];
    int base = blockIdx.x * 1024 + threadIdx.x * 4;
    int v[4];
    int s = 0;
#pragma unroll
    for (int k = 0; k < 4; ++k) {
        int idx = base + k;
        v[k] = (idx < n) ? deg[idx] : 0;
        s += v[k];
    }
    ssum[threadIdx.x] = s;
    __syncthreads();
    for (int off = 1; off < 256; off <<= 1) {
        int t = (threadIdx.x >= off) ? ssum[threadIdx.x - off] : 0;
        __syncthreads();
        ssum[threadIdx.x] += t;
        __syncthreads();
    }
    int ex = (threadIdx.x > 0 ? ssum[threadIdx.x - 1] : 0) + bsum[blockIdx.x];
#pragma unroll
    for (int k = 0; k < 4; ++k) {
        int idx = base + k;
        if (idx < n) rowptr[idx] = ex;
        ex += v[k];
    }
}

// ---------------- CSR fill (no atomic, adj only) -----------------------------
__global__ void fill_kernel(const int* __restrict__ src, const int* __restrict__ dst,
                            const int* __restrict__ pos, const int* __restrict__ rowptr,
                            int* __restrict__ adj, int E) {
    int e = blockIdx.x * blockDim.x + threadIdx.x;
    if (e >= E) return;
    adj[rowptr[dst[e]] + pos[e]] = src[e];
}

// ---------------- MFMA dense transform -> hs = dinv * (in @ W), bf16 rows ----
// FIN fixed at 64. IN_MODE: 0 = fp32 rows; 1 = bf16 [n][64] rows.
template <int FOUT, int CT, int IN_MODE, int MT>
__global__ void gemm_mfma_kernel(const void* __restrict__ in_, const unsigned short* __restrict__ wf,
                                 const float* __restrict__ dinv, unsigned int* __restrict__ hs32,
                                 int n) {
    int lane = threadIdx.x & 63;
    int tile0 = (blockIdx.x * 4 + (threadIdx.x >> 6)) * MT;
    if (tile0 * 16 >= n) return;
    bf16x8 bfrag[CT][2];
#pragma unroll
    for (int ct = 0; ct < CT; ++ct)
#pragma unroll
        for (int kh = 0; kh < 2; ++kh)
            bfrag[ct][kh] = *(const bf16x8*)(wf + ((size_t)(ct * 2 + kh) * 64 + lane) * 8);

    int rloc = lane & 15;   // A row within tile
    int koct = lane >> 4;   // k octet 0..3
    for (int t = 0; t < MT; ++t) {
        int rbase = (tile0 + t) * 16;
        if (rbase >= n) break;
        int r = rbase + rloc;
        int rc = (r < n) ? r : (n - 1);
        bf16x8 af0, af1;
        if (IN_MODE == 1) {
            const unsigned short* inb = (const unsigned short*)in_;
            af0 = *(const bf16x8*)(inb + (size_t)rc * 64 + koct * 8);       // k 0..31
            af1 = *(const bf16x8*)(inb + (size_t)rc * 64 + 32 + koct * 8);  // k 32..63
        } else {
            const float* inf = (const float*)in_;
            const float* ap = inf + (size_t)rc * 64 + koct * 8;
            float av[16];
            *(float4*)(av + 0)  = *(const float4*)(ap + 0);
            *(float4*)(av + 4)  = *(const float4*)(ap + 4);
            *(float4*)(av + 8)  = *(const float4*)(ap + 32);
            *(float4*)(av + 12) = *(const float4*)(ap + 36);
#pragma unroll
            for (int j = 0; j < 8; ++j) {
                af0[j] = (short)bf16rne(av[j]);
                af1[j] = (short)bf16rne(av[8 + j]);
            }
        }
#pragma unroll
        for (int ct = 0; ct < CT; ++ct) {
            f32x4 acc = {0.0f, 0.0f, 0.0f, 0.0f};
            acc = __builtin_amdgcn_mfma_f32_16x16x32_bf16(af0, bfrag[ct][0], acc, 0, 0, 0);
            acc = __builtin_amdgcn_mfma_f32_16x16x32_bf16(af1, bfrag[ct][1], acc, 0, 0, 0);
            int col = ct * 16 + rloc;  // D col = lane&15
#pragma unroll
            for (int reg = 0; reg < 4; ++reg) {
                int row = rbase + koct * 4 + reg;  // D row = (lane>>4)*4+reg
                float dd = dinv[(row < n) ? row : (n - 1)];
                float v = acc[reg] * dd;
                float po = __shfl_xor(v, 1, 64);   // partner column (lane^1)
                if (row < n && ((lane & 1) == 0) && col < FOUT) {
                    hs32[(size_t)row * (FOUT / 2) + (col >> 1)] = bf16rne(v) | (bf16rne(po) << 16);
                }
            }
        }
    }
}

// ---------------- gather full-row pass: [n][64] bf16 rows --------------------
// 16-lane quarter per node; lane i handles features {4i..4i+3} (one uint2).
// sum = hs[v] + sum_{e: dst=v} hs[src_e]
// OMODE 0: outA = bf16(relu(dinv[v]*sum + b))
// OMODE 1: same + outB = bf16(dinv[v] * relu(...))   (pre-scaled for next agg)
// OMODE 2: outA = bf16(sum)                           (raw; scale folded later)
template <int OMODE, int TAG>
__global__ void gather_full_kernel(const int* __restrict__ rowptr, const int* __restrict__ deg,
                                   const int* __restrict__ adj, const uint2* __restrict__ h2,
                                   const float* __restrict__ dinv, const float* __restrict__ b,
                                   uint2* __restrict__ outA, uint2* __restrict__ outB, int n) {
    int lane = threadIdx.x & 63;
    int wid = threadIdx.x >> 6;
    int i = lane & 15;
    int qbase = lane & ~15;  // first lane of this quarter
    int node = blockIdx.x * 16 + wid * 4 + (lane >> 4);
    if (node >= n) return;
    uint2 hv = h2[(size_t)node * 16 + i];  // self term
    float a0 = bf2f(hv.x), a1 = bf2f_hi(hv.x);
    float a2 = bf2f(hv.y), a3 = bf2f_hi(hv.y);
    int r0 = rowptr[node];
    int cnt = deg[node];
    int nf = cnt & ~15;
    for (int j0 = 0; j0 < nf; j0 += 16) {
        int sv = adj[r0 + j0 + i];  // coalesced: 16 adj entries per quarter
#pragma unroll
        for (int t = 0; t < 16; ++t) {
            int s = __shfl(sv, qbase + t, 64);  // broadcast within quarter (ds_bpermute)
            uint2 v = h2[(size_t)s * 16 + i];
            a0 += bf2f(v.x); a1 += bf2f_hi(v.x);
            a2 += bf2f(v.y); a3 += bf2f_hi(v.y);
        }
    }
    {   // tail (adj is padded by 64 ints so this never reads OOB)
        int sv = adj[r0 + nf + i];
#pragma unroll
        for (int t = 0; t < 16; ++t) {
            if (nf + t < cnt) {   // quarter-uniform guard
                int s = __shfl(sv, qbase + t, 64);
                uint2 v = h2[(size_t)s * 16 + i];
                a0 += bf2f(v.x); a1 += bf2f_hi(v.x);
                a2 += bf2f(v.y); a3 += bf2f_hi(v.y);
            }
        }
    }
    if (OMODE == 2) {
        uint2 o;
        o.x = bf16rne(a0) | (bf16rne(a1) << 16);
        o.y = bf16rne(a2) | (bf16rne(a3) << 16);
        outA[(size_t)node * 16 + i] = o;
    } else {
        float dd = dinv[node];
        float4 bv = ((const float4*)b)[i];
        float t0 = fmaxf(fmaf(a0, dd, bv.x), 0.0f);
        float t1 = fmaxf(fmaf(a1, dd, bv.y), 0.0f);
        float t2 = fmaxf(fmaf(a2, dd, bv.z), 0.0f);
        float t3 = fmaxf(fmaf(a3, dd, bv.w), 0.0f);
        uint2 o;
        o.x = bf16rne(t0) | (bf16rne(t1) << 16);
        o.y = bf16rne(t2) | (bf16rne(t3) << 16);
        outA[(size_t)node * 16 + i] = o;
        if (OMODE == 1) {
            uint2 ob;
            ob.x = bf16rne(t0 * dd) | (bf16rne(t1 * dd) << 16);
            ob.y = bf16rne(t2 * dd) | (bf16rne(t3 * dd) << 16);
            outB[(size_t)node * 16 + i] = ob;
        }
    }
}

// ---------------- final GEMM40 + dinv + bias + fused log_softmax -------------
// in = aggregated rows [n][64] bf16; out = log_softmax(dinv[row]*(agg@W2) + b2)
template <int MT>
__global__ void gemm40_lsm_kernel(const unsigned int* __restrict__ in_,
                                  const unsigned short* __restrict__ wf,
                                  const float* __restrict__ dinv, const float* __restrict__ b,
                                  float* __restrict__ out, int n) {
    const int CT = 3;
    int lane = threadIdx.x & 63;
    int tile0 = (blockIdx.x * 4 + (threadIdx.x >> 6)) * MT;
    if (tile0 * 16 >= n) return;
    bf16x8 bfrag[CT][2];
#pragma unroll
    for (int ct = 0; ct < CT; ++ct)
#pragma unroll
        for (int kh = 0; kh < 2; ++kh)
            bfrag[ct][kh] = *(const bf16x8*)(wf + ((size_t)(ct * 2 + kh) * 64 + lane) * 8);

    int rloc = lane & 15;
    int koct = lane >> 4;
    float bc[CT];
#pragma unroll
    for (int ct = 0; ct < CT; ++ct) {
        int col = ct * 16 + rloc;
        bc[ct] = (col < 40) ? b[col] : -INFINITY;
    }
    const unsigned short* inb = (const unsigned short*)in_;
    for (int t = 0; t < MT; ++t) {
        int rbase = (tile0 + t) * 16;
        if (rbase >= n) break;
        int r = rbase + rloc;
        int rc = (r < n) ? r : (n - 1);
        bf16x8 af0 = *(const bf16x8*)(inb + (size_t)rc * 64 + koct * 8);
        bf16x8 af1 = *(const bf16x8*)(inb + (size_t)rc * 64 + 32 + koct * 8);
        f32x4 acc[CT];
#pragma unroll
        for (int ct = 0; ct < CT; ++ct) {
            f32x4 a = {0.0f, 0.0f, 0.0f, 0.0f};
            a = __builtin_amdgcn_mfma_f32_16x16x32_bf16(af0, bfrag[ct][0], a, 0, 0, 0);
            a = __builtin_amdgcn_mfma_f32_16x16x32_bf16(af1, bfrag[ct][1], a, 0, 0, 0);
            acc[ct] = a;
        }
#pragma unroll
        for (int reg = 0; reg < 4; ++reg) {
            int row = rbase + koct * 4 + reg;
            float dd = dinv[(row < n) ? row : (n - 1)];
            float v0 = fmaf(acc[0][reg], dd, bc[0]);
            float v1 = fmaf(acc[1][reg], dd, bc[1]);
            float v2 = fmaf(acc[2][reg], dd, bc[2]);
            float m = fmaxf(fmaxf(v0, v1), v2);
#pragma unroll
            for (int off = 8; off >= 1; off >>= 1) m = fmaxf(m, __shfl_xor(m, off, 16));
            float es = expf(v0 - m) + expf(v1 - m) + ((v2 == -INFINITY) ? 0.0f : expf(v2 - m));
#pragma unroll
            for (int off = 8; off >= 1; off >>= 1) es += __shfl_xor(es, off, 16);
            float ls = m + logf(es);
            if (row < n) {
                out[(size_t)row * 40 + rloc] = v0 - ls;
                out[(size_t)row * 40 + 16 + rloc] = v1 - ls;
                if (rloc < 8) out[(size_t)row * 40 + 32 + rloc] = v2 - ls;
            }
        }
    }
}

extern "C" void kernel_launch(void* const* d_in, const int* in_sizes, int n_in,
                              void* d_out, int out_size, void* d_ws, size_t ws_size,
                              hipStream_t stream) {
    const float* x  = (const float*)d_in[0];
    const int*   ei = (const int*)d_in[1];
    const float* W0 = (const float*)d_in[2];
    const float* b0 = (const float*)d_in[3];
    const float* W1 = (const float*)d_in[4];
    const float* b1 = (const float*)d_in[5];
    const float* W2 = (const float*)d_in[6];
    const float* b2 = (const float*)d_in[7];
    float* out = (float*)d_out;

    const int H   = in_sizes[3];            // 64
    const int FIN = in_sizes[2] / H;        // 64
    const int n   = in_sizes[0] / FIN;      // 50000
    const int E   = in_sizes[1] / 2;        // 800000
    (void)FIN;

    const int* srcp = ei;
    const int* dstp = ei + E;

    char* ws = (char*)d_ws;
    size_t off = 0;
    int*   deg    = (int*)(ws + off);   off += ws_align((size_t)n * 4);
    int*   rowptr = (int*)(ws + off);   off += ws_align((size_t)n * 4);
    int*   bsum   = (int*)(ws + off);   off += ws_align(256 * 4);
    float* dinv   = (float*)(ws + off); off += ws_align((size_t)n * 4);
    int*   pos    = (int*)(ws + off);   off += ws_align((size_t)E * 4);
    int*   adj    = (int*)(ws + off);   off += ws_align((size_t)(E + 64) * 4);  // +64 pad for tail reads
    unsigned int* hs    = (unsigned int*)(ws + off); off += ws_align((size_t)n * H * 2);  // [n][64] bf16 rows
    unsigned int* actB  = (unsigned int*)(ws + off); off += ws_align((size_t)n * H * 2);
    unsigned int* actBs = (unsigned int*)(ws + off); off += ws_align((size_t)n * H * 2);
    unsigned short* wf0 = (unsigned short*)(ws + off); off += ws_align(4 * 2 * 64 * 8 * 2);
    unsigned short* wf1 = (unsigned short*)(ws + off); off += ws_align(4 * 2 * 64 * 8 * 2);
    unsigned short* wf2 = (unsigned short*)(ws + off); off += ws_align(3 * 2 * 64 * 8 * 2);

    // CSR build
    zero_kernel<<<(n + 255) / 256, 256, 0, stream>>>(deg, n);
    deg_pos_kernel<<<(E + 255) / 256, 256, 0, stream>>>(dstp, E, deg, pos);
    int nscan = (n + 1023) / 1024;  // 49
    scan1_dinv_kernel<<<nscan, 256, 0, stream>>>(deg, bsum, dinv, n);
    scan2_wconv_kernel<<<4, 256, 0, stream>>>(bsum, nscan, W0, W1, W2, wf0, wf1, wf2);
    scan3_kernel<<<nscan, 256, 0, stream>>>(deg, bsum, rowptr, n);
    fill_kernel<<<(E + 255) / 256, 256, 0, stream>>>(srcp, dstp, pos, rowptr, adj, E);

    const int MT = 2;
    int tiles = (n + 15) / 16;                        // 3125
    int gemm_grid = (tiles + 4 * MT - 1) / (4 * MT);  // 391
    int node_grid = (n + 15) / 16;                    // 16 nodes/block

    // layer 0: gemm -> hs ; gather -> actB (relu bf16)
    gemm_mfma_kernel<64, 4, 0, MT><<<gemm_grid, 256, 0, stream>>>(x, wf0, dinv, hs, n);
    gather_full_kernel<0, 0><<<node_grid, 256, 0, stream>>>(rowptr, deg, adj, (const uint2*)hs, dinv, b0, (uint2*)actB, nullptr, n);
    // layer 1: gemm -> hs ; gather -> actB + actBs (dinv-prescaled)
    gemm_mfma_kernel<64, 4, 1, MT><<<gemm_grid, 256, 0, stream>>>(actB, wf1, dinv, hs, n);
    gather_full_kernel<1, 1><<<node_grid, 256, 0, stream>>>(rowptr, deg, adj, (const uint2*)hs, dinv, b1, (uint2*)actB, (uint2*)actBs, n);
    // layer 2 (commuted): aggregate actBs -> hs (raw sums) ; gemm40 + lsm -> out
    gather_full_kernel<2, 2><<<node_grid, 256, 0, stream>>>(rowptr, deg, adj, (const uint2*)actBs, nullptr, nullptr, (uint2*)hs, nullptr, n);
    gemm40_lsm_kernel<MT><<<gemm_grid, 256, 0, stream>>>(hs, wf2, dinv, b2, out, n);
}

// Round 12
// 170.888 us; speedup vs baseline: 1.2633x; 1.0387x over previous
//
#include <hip/hip_runtime.h>
#include <math.h>

static inline size_t ws_align(size_t x) { return (x + 255) & ~size_t(255); }

typedef float f32x4 __attribute__((ext_vector_type(4)));
typedef short bf16x8 __attribute__((ext_vector_type(8)));

__device__ inline unsigned int bf16rne(float f) {
    unsigned int u = __float_as_uint(f);
    u += 0x7FFFu + ((u >> 16) & 1u);
    return u >> 16;
}
__device__ inline float bf2f(unsigned int u) {  // low 16 bits = bf16
    return __uint_as_float(u << 16);
}
__device__ inline float bf2f_hi(unsigned int u) {  // high 16 bits
    return __uint_as_float(u & 0xFFFF0000u);
}

// ---------------- zero deg ----------------
__global__ void zero_kernel(int* __restrict__ p, int n) {
    int i = blockIdx.x * blockDim.x + threadIdx.x;
    if (i < n) p[i] = 0;
}

// ---------------- degree histogram + per-edge slot ----------------
__global__ void deg_pos_kernel(const int* __restrict__ dst, int E,
                               int* __restrict__ deg, int* __restrict__ pos) {
    int e = blockIdx.x * blockDim.x + threadIdx.x;
    if (e < E) pos[e] = atomicAdd(&deg[dst[e]], 1);
}

// ---------------- scan pass 1 (block sums) + dinv fused ----------------
__global__ void scan1_dinv_kernel(const int* __restrict__ deg, int* __restrict__ bsum,
                                  float* __restrict__ dinv, int n) {
    __shared__ int sdata[256];
    int base = blockIdx.x * 1024;
    int sum = 0;
    for (int i = threadIdx.x; i < 1024; i += 256) {
        int idx = base + i;
        if (idx < n) {
            int d = deg[idx];
            sum += d;
            dinv[idx] = rsqrtf((float)(d + 1));  // +1 self-loop
        }
    }
    sdata[threadIdx.x] = sum;
    __syncthreads();
    for (int s = 128; s > 0; s >>= 1) {
        if (threadIdx.x < s) sdata[threadIdx.x] += sdata[threadIdx.x + s];
        __syncthreads();
    }
    if (threadIdx.x == 0) bsum[blockIdx.x] = sdata[0];
}

// ---------------- W -> MFMA B-fragment layout (device body) ------------------
template <int FOUT, int CT>
__device__ void wconv_body(const float* __restrict__ W, unsigned short* __restrict__ wf) {
    for (int idx = threadIdx.x; idx < CT * 2 * 64 * 8; idx += 256) {
        int j = idx & 7;
        int lane = (idx >> 3) & 63;
        int kh = (idx >> 9) & 1;
        int ct = idx >> 10;
        int k = kh * 32 + ((lane >> 4) * 8) + j;
        int col = ct * 16 + (lane & 15);
        float v = (col < FOUT) ? W[k * FOUT + col] : 0.0f;
        wf[idx] = (unsigned short)bf16rne(v);
    }
}

// ---------------- scan pass 2 (1 block) + wconv x3 (blocks 1..3) -------------
__global__ void scan2_wconv_kernel(int* __restrict__ bsum, int nb,
                                   const float* __restrict__ W0, const float* __restrict__ W1,
                                   const float* __restrict__ W2,
                                   unsigned short* __restrict__ wf0, unsigned short* __restrict__ wf1,
                                   unsigned short* __restrict__ wf2) {
    if (blockIdx.x == 1) { wconv_body<64, 4>(W0, wf0); return; }
    if (blockIdx.x == 2) { wconv_body<64, 4>(W1, wf1); return; }
    if (blockIdx.x == 3) { wconv_body<40, 3>(W2, wf2); return; }
    __shared__ int sdata[256];
    int v = (threadIdx.x < nb) ? bsum[threadIdx.x] : 0;
    sdata[threadIdx.x] = v;
    __syncthreads();
    for (int off = 1; off < 256; off <<= 1) {
        int t = (threadIdx.x >= off) ? sdata[threadIdx.x - off] : 0;
        __syncthreads();
        sdata[threadIdx.x] += t;
        __syncthreads();
    }
    if (threadIdx.x < nb) bsum[threadIdx.x] = sdata[threadIdx.x] - v;  // exclusive
}

__global__ void scan3_kernel(const int* __restrict__ deg, const int* __restrict__ bsum,
                             int* __restrict__ rowptr, int n) {
    __shared__ int ssum[256];
    int base = blockIdx.x * 1024 + threadIdx.x * 4;
    int v[4];
    int s = 0;
#pragma unroll
    for (int k = 0; k < 4; ++k) {
        int idx = base + k;
        v[k] = (idx < n) ? deg[idx] : 0;
        s += v[k];
    }
    ssum[threadIdx.x] = s;
    __syncthreads();
    for (int off = 1; off < 256; off <<= 1) {
        int t = (threadIdx.x >= off) ? ssum[threadIdx.x - off] : 0;
        __syncthreads();
        ssum[threadIdx.x] += t;
        __syncthreads();
    }
    int ex = (threadIdx.x > 0 ? ssum[threadIdx.x - 1] : 0) + bsum[blockIdx.x];
#pragma unroll
    for (int k = 0; k < 4; ++k) {
        int idx = base + k;
        if (idx < n) rowptr[idx] = ex;
        ex += v[k];
    }
}

// ---------------- MFMA dense-transform device body (one 16-row tile) ---------
// hs = dinv * (in @ W) as bf16 [n][FOUT] rows. IN_MODE 0 = fp32, 1 = bf16.
template <int FOUT, int CT, int IN_MODE>
__device__ void gemm_body(int tile, const void* __restrict__ in_,
                          const unsigned short* __restrict__ wf,
                          const float* __restrict__ dinv, unsigned int* __restrict__ hs32,
                          int n, int lane) {
    bf16x8 bfrag[CT][2];
#pragma unroll
    for (int ct = 0; ct < CT; ++ct)
#pragma unroll
        for (int kh = 0; kh < 2; ++kh)
            bfrag[ct][kh] = *(const bf16x8*)(wf + ((size_t)(ct * 2 + kh) * 64 + lane) * 8);

    int rloc = lane & 15;   // A row within tile
    int koct = lane >> 4;   // k octet 0..3
    int rbase = tile * 16;
    int r = rbase + rloc;
    int rc = (r < n) ? r : (n - 1);
    bf16x8 af0, af1;
    if (IN_MODE == 1) {
        const unsigned short* inb = (const unsigned short*)in_;
        af0 = *(const bf16x8*)(inb + (size_t)rc * 64 + koct * 8);       // k 0..31
        af1 = *(const bf16x8*)(inb + (size_t)rc * 64 + 32 + koct * 8);  // k 32..63
    } else {
        const float* inf = (const float*)in_;
        const float* ap = inf + (size_t)rc * 64 + koct * 8;
        float av[16];
        *(float4*)(av + 0)  = *(const float4*)(ap + 0);
        *(float4*)(av + 4)  = *(const float4*)(ap + 4);
        *(float4*)(av + 8)  = *(const float4*)(ap + 32);
        *(float4*)(av + 12) = *(const float4*)(ap + 36);
#pragma unroll
        for (int j = 0; j < 8; ++j) {
            af0[j] = (short)bf16rne(av[j]);
            af1[j] = (short)bf16rne(av[8 + j]);
        }
    }
#pragma unroll
    for (int ct = 0; ct < CT; ++ct) {
        f32x4 acc = {0.0f, 0.0f, 0.0f, 0.0f};
        acc = __builtin_amdgcn_mfma_f32_16x16x32_bf16(af0, bfrag[ct][0], acc, 0, 0, 0);
        acc = __builtin_amdgcn_mfma_f32_16x16x32_bf16(af1, bfrag[ct][1], acc, 0, 0, 0);
        int col = ct * 16 + rloc;  // D col = lane&15
#pragma unroll
        for (int reg = 0; reg < 4; ++reg) {
            int row = rbase + koct * 4 + reg;  // D row = (lane>>4)*4+reg
            float dd = dinv[(row < n) ? row : (n - 1)];
            float v = acc[reg] * dd;
            float po = __shfl_xor(v, 1, 64);   // partner column (lane^1)
            if (row < n && ((lane & 1) == 0) && col < FOUT) {
                hs32[(size_t)row * (FOUT / 2) + (col >> 1)] = bf16rne(v) | (bf16rne(po) << 16);
            }
        }
    }
}

template <int FOUT, int CT, int IN_MODE>
__global__ void gemm_mfma_kernel(const void* __restrict__ in_, const unsigned short* __restrict__ wf,
                                 const float* __restrict__ dinv, unsigned int* __restrict__ hs32,
                                 int n) {
    int lane = threadIdx.x & 63;
    int tile = blockIdx.x * 4 + (threadIdx.x >> 6);
    if (tile * 16 < n)
        gemm_body<FOUT, CT, IN_MODE>(tile, in_, wf, dinv, hs32, n, lane);
}

// ---------------- fused CSR fill + layer-0 gemm ------------------------------
__global__ void fill_gemm0_kernel(const int* __restrict__ src, const int* __restrict__ dst,
                                  const int* __restrict__ pos, const int* __restrict__ rowptr,
                                  int* __restrict__ adj, int E, int nfb,
                                  const float* __restrict__ x, const unsigned short* __restrict__ wf0,
                                  const float* __restrict__ dinv, unsigned int* __restrict__ hs,
                                  int n) {
    if ((int)blockIdx.x < nfb) {
        int e = blockIdx.x * blockDim.x + threadIdx.x;
        if (e < E) adj[rowptr[dst[e]] + pos[e]] = src[e];
    } else {
        int lane = threadIdx.x & 63;
        int tile = (blockIdx.x - nfb) * 4 + (threadIdx.x >> 6);
        if (tile * 16 < n)
            gemm_body<64, 4, 0>(tile, x, wf0, dinv, hs, n, lane);
    }
}

// ---------------- gather full-row pass: [n][64] bf16 rows --------------------
// 16-lane quarter per node; lane i handles features {4i..4i+3} (one uint2).
// sum = hs[v] + sum_{e: dst=v} hs[src_e]
// OMODE 0: outA = bf16(relu(dinv[v]*sum + b))
// OMODE 1: same + outB = bf16(dinv[v] * relu(...))   (pre-scaled for next agg)
// OMODE 2: outA = bf16(sum)                           (raw; scale folded later)
__device__ inline void acc_edge(const uint2* __restrict__ h2, int s, int i,
                                float& a0, float& a1, float& a2, float& a3) {
    uint2 v = h2[(size_t)s * 16 + i];
    a0 += bf2f(v.x); a1 += bf2f_hi(v.x);
    a2 += bf2f(v.y); a3 += bf2f_hi(v.y);
}

template <int OMODE, int TAG>
__global__ void gather_full_kernel(const int* __restrict__ rowptr, const int* __restrict__ deg,
                                   const int* __restrict__ adj, const uint2* __restrict__ h2,
                                   const float* __restrict__ dinv, const float* __restrict__ b,
                                   uint2* __restrict__ outA, uint2* __restrict__ outB, int n) {
    int lane = threadIdx.x & 63;
    int wid = threadIdx.x >> 6;
    int i = lane & 15;
    int qbase = lane & ~15;  // first lane of this quarter
    int node = blockIdx.x * 16 + wid * 4 + (lane >> 4);
    if (node >= n) return;
    uint2 hv = h2[(size_t)node * 16 + i];  // self term
    float a0 = bf2f(hv.x), a1 = bf2f_hi(hv.x);
    float a2 = bf2f(hv.y), a3 = bf2f_hi(hv.y);
    int r0 = rowptr[node];
    int cnt = deg[node];
    int nf = cnt & ~15;
    for (int j0 = 0; j0 < nf; j0 += 16) {
        int sv = adj[r0 + j0 + i];  // coalesced: 16 adj entries per quarter
#pragma unroll
        for (int t = 0; t < 16; ++t) {
            int s = __shfl(sv, qbase + t, 64);  // broadcast within quarter
            acc_edge(h2, s, i, a0, a1, a2, a3);
        }
    }
    int rem = cnt - nf;  // 0..15
    if (rem) {
        int sv = adj[r0 + nf + i];  // adj padded by 64 ints -> safe
#pragma unroll
        for (int tb = 0; tb < 16; tb += 4) {
            if (tb < rem) {          // quarter-uniform chunk guard
#pragma unroll
                for (int t = tb; t < tb + 4; ++t) {
                    if (t < rem) {   // quarter-uniform
                        int s = __shfl(sv, qbase + t, 64);
                        acc_edge(h2, s, i, a0, a1, a2, a3);
                    }
                }
            }
        }
    }
    if (OMODE == 2) {
        uint2 o;
        o.x = bf16rne(a0) | (bf16rne(a1) << 16);
        o.y = bf16rne(a2) | (bf16rne(a3) << 16);
        outA[(size_t)node * 16 + i] = o;
    } else {
        float dd = dinv[node];
        float4 bv = ((const float4*)b)[i];
        float t0 = fmaxf(fmaf(a0, dd, bv.x), 0.0f);
        float t1 = fmaxf(fmaf(a1, dd, bv.y), 0.0f);
        float t2 = fmaxf(fmaf(a2, dd, bv.z), 0.0f);
        float t3 = fmaxf(fmaf(a3, dd, bv.w), 0.0f);
        uint2 o;
        o.x = bf16rne(t0) | (bf16rne(t1) << 16);
        o.y = bf16rne(t2) | (bf16rne(t3) << 16);
        outA[(size_t)node * 16 + i] = o;
        if (OMODE == 1) {
            uint2 ob;
            ob.x = bf16rne(t0 * dd) | (bf16rne(t1 * dd) << 16);
            ob.y = bf16rne(t2 * dd) | (bf16rne(t3 * dd) << 16);
            outB[(size_t)node * 16 + i] = ob;
        }
    }
}

// ---------------- final GEMM40 + dinv + bias + fused log_softmax -------------
// in = aggregated rows [n][64] bf16; out = log_softmax(dinv[row]*(agg@W2) + b2)
__global__ void gemm40_lsm_kernel(const unsigned int* __restrict__ in_,
                                  const unsigned short* __restrict__ wf,
                                  const float* __restrict__ dinv, const float* __restrict__ b,
                                  float* __restrict__ out, int n) {
    const int CT = 3;
    int lane = threadIdx.x & 63;
    int tile = blockIdx.x * 4 + (threadIdx.x >> 6);
    if (tile * 16 >= n) return;
    bf16x8 bfrag[CT][2];
#pragma unroll
    for (int ct = 0; ct < CT; ++ct)
#pragma unroll
        for (int kh = 0; kh < 2; ++kh)
            bfrag[ct][kh] = *(const bf16x8*)(wf + ((size_t)(ct * 2 + kh) * 64 + lane) * 8);

    int rloc = lane & 15;
    int koct = lane >> 4;
    float bc[CT];
#pragma unroll
    for (int ct = 0; ct < CT; ++ct) {
        int col = ct * 16 + rloc;
        bc[ct] = (col < 40) ? b[col] : -INFINITY;
    }
    const unsigned short* inb = (const unsigned short*)in_;
    int rbase = tile * 16;
    int r = rbase + rloc;
    int rc = (r < n) ? r : (n - 1);
    bf16x8 af0 = *(const bf16x8*)(inb + (size_t)rc * 64 + koct * 8);
    bf16x8 af1 = *(const bf16x8*)(inb + (size_t)rc * 64 + 32 + koct * 8);
    f32x4 acc[CT];
#pragma unroll
    for (int ct = 0; ct < CT; ++ct) {
        f32x4 a = {0.0f, 0.0f, 0.0f, 0.0f};
        a = __builtin_amdgcn_mfma_f32_16x16x32_bf16(af0, bfrag[ct][0], a, 0, 0, 0);
        a = __builtin_amdgcn_mfma_f32_16x16x32_bf16(af1, bfrag[ct][1], a, 0, 0, 0);
        acc[ct] = a;
    }
#pragma unroll
    for (int reg = 0; reg < 4; ++reg) {
        int row = rbase + koct * 4 + reg;
        float dd = dinv[(row < n) ? row : (n - 1)];
        float v0 = fmaf(acc[0][reg], dd, bc[0]);
        float v1 = fmaf(acc[1][reg], dd, bc[1]);
        float v2 = fmaf(acc[2][reg], dd, bc[2]);
        float m = fmaxf(fmaxf(v0, v1), v2);
#pragma unroll
        for (int off = 8; off >= 1; off >>= 1) m = fmaxf(m, __shfl_xor(m, off, 16));
        float es = expf(v0 - m) + expf(v1 - m) + ((v2 == -INFINITY) ? 0.0f : expf(v2 - m));
#pragma unroll
        for (int off = 8; off >= 1; off >>= 1) es += __shfl_xor(es, off, 16);
        float ls = m + logf(es);
        if (row < n) {
            out[(size_t)row * 40 + rloc] = v0 - ls;
            out[(size_t)row * 40 + 16 + rloc] = v1 - ls;
            if (rloc < 8) out[(size_t)row * 40 + 32 + rloc] = v2 - ls;
        }
    }
}

extern "C" void kernel_launch(void* const* d_in, const int* in_sizes, int n_in,
                              void* d_out, int out_size, void* d_ws, size_t ws_size,
                              hipStream_t stream) {
    const float* x  = (const float*)d_in[0];
    const int*   ei = (const int*)d_in[1];
    const float* W0 = (const float*)d_in[2];
    const float* b0 = (const float*)d_in[3];
    const float* W1 = (const float*)d_in[4];
    const float* b1 = (const float*)d_in[5];
    const float* W2 = (const float*)d_in[6];
    const float* b2 = (const float*)d_in[7];
    float* out = (float*)d_out;

    const int H   = in_sizes[3];            // 64
    const int FIN = in_sizes[2] / H;        // 64
    const int n   = in_sizes[0] / FIN;      // 50000
    const int E   = in_sizes[1] / 2;        // 800000
    (void)FIN;

    const int* srcp = ei;
    const int* dstp = ei + E;

    char* ws = (char*)d_ws;
    size_t off = 0;
    int*   deg    = (int*)(ws + off);   off += ws_align((size_t)n * 4);
    int*   rowptr = (int*)(ws + off);   off += ws_align((size_t)n * 4);
    int*   bsum   = (int*)(ws + off);   off += ws_align(256 * 4);
    float* dinv   = (float*)(ws + off); off += ws_align((size_t)n * 4);
    int*   pos    = (int*)(ws + off);   off += ws_align((size_t)E * 4);
    int*   adj    = (int*)(ws + off);   off += ws_align((size_t)(E + 64) * 4);  // +64 pad for tail reads
    unsigned int* hs    = (unsigned int*)(ws + off); off += ws_align((size_t)n * H * 2);  // [n][64] bf16 rows
    unsigned int* actB  = (unsigned int*)(ws + off); off += ws_align((size_t)n * H * 2);
    unsigned int* actBs = (unsigned int*)(ws + off); off += ws_align((size_t)n * H * 2);
    unsigned short* wf0 = (unsigned short*)(ws + off); off += ws_align(4 * 2 * 64 * 8 * 2);
    unsigned short* wf1 = (unsigned short*)(ws + off); off += ws_align(4 * 2 * 64 * 8 * 2);
    unsigned short* wf2 = (unsigned short*)(ws + off); off += ws_align(3 * 2 * 64 * 8 * 2);

    // CSR build
    zero_kernel<<<(n + 255) / 256, 256, 0, stream>>>(deg, n);
    deg_pos_kernel<<<(E + 255) / 256, 256, 0, stream>>>(dstp, E, deg, pos);
    int nscan = (n + 1023) / 1024;  // 49
    scan1_dinv_kernel<<<nscan, 256, 0, stream>>>(deg, bsum, dinv, n);
    scan2_wconv_kernel<<<4, 256, 0, stream>>>(bsum, nscan, W0, W1, W2, wf0, wf1, wf2);
    scan3_kernel<<<nscan, 256, 0, stream>>>(deg, bsum, rowptr, n);

    int tiles = (n + 15) / 16;                 // 3125
    int gemm_grid = (tiles + 3) / 4;           // 782 blocks, 1 tile/wave
    int fill_grid = (E + 255) / 256;           // 3125
    int node_grid = (n + 15) / 16;             // 16 nodes/block

    // fused: CSR fill + layer-0 gemm (independent work, one launch)
    fill_gemm0_kernel<<<fill_grid + gemm_grid, 256, 0, stream>>>(
        srcp, dstp, pos, rowptr, adj, E, fill_grid, x, wf0, dinv, hs, n);

    // layer 0 gather -> actB (relu bf16)
    gather_full_kernel<0, 0><<<node_grid, 256, 0, stream>>>(rowptr, deg, adj, (const uint2*)hs, dinv, b0, (uint2*)actB, nullptr, n);
    // layer 1: gemm -> hs ; gather -> actB + actBs (dinv-prescaled)
    gemm_mfma_kernel<64, 4, 1><<<gemm_grid, 256, 0, stream>>>(actB, wf1, dinv, hs, n);
    gather_full_kernel<1, 1><<<node_grid, 256, 0, stream>>>(rowptr, deg, adj, (const uint2*)hs, dinv, b1, (uint2*)actB, (uint2*)actBs, n);
    // layer 2 (commuted): aggregate actBs -> hs (raw sums) ; gemm40 + lsm -> out
    gather_full_kernel<2, 2><<<node_grid, 256, 0, stream>>>(rowptr, deg, adj, (const uint2*)actBs, nullptr, nullptr, (uint2*)hs, nullptr, n);
    gemm40_lsm_kernel<<<gemm_grid, 256, 0, stream>>>(hs, wf2, dinv, b2, out, n);
}

// Round 13
// 153.648 us; speedup vs baseline: 1.4050x; 1.1122x over previous
//
#include <hip/hip_runtime.h>
#include <math.h>

static inline size_t ws_align(size_t x) { return (x + 255) & ~size_t(255); }

typedef float f32x4 __attribute__((ext_vector_type(4)));
typedef short bf16x8 __attribute__((ext_vector_type(8)));

__device__ inline unsigned int bf16rne(float f) {
    unsigned int u = __float_as_uint(f);
    u += 0x7FFFu + ((u >> 16) & 1u);
    return u >> 16;
}
__device__ inline float bf2f(unsigned int u) {  // low 16 bits = bf16
    return __uint_as_float(u << 16);
}
__device__ inline float bf2f_hi(unsigned int u) {  // high 16 bits
    return __uint_as_float(u & 0xFFFF0000u);
}

// ---------------- zero deg ----------------
__global__ void zero_kernel(int* __restrict__ p, int n) {
    int i = blockIdx.x * blockDim.x + threadIdx.x;
    if (i < n) p[i] = 0;
}

// ---------------- degree histogram + per-edge slot ----------------
__global__ void deg_pos_kernel(const int* __restrict__ dst, int E,
                               int* __restrict__ deg, int* __restrict__ pos) {
    int e = blockIdx.x * blockDim.x + threadIdx.x;
    if (e < E) pos[e] = atomicAdd(&deg[dst[e]], 1);
}

// ---------------- scan pass 1 (block sums) + dinv fused ----------------
__global__ void scan1_dinv_kernel(const int* __restrict__ deg, int* __restrict__ bsum,
                                  float* __restrict__ dinv, int n) {
    __shared__ int sdata[256];
    int base = blockIdx.x * 1024;
    int sum = 0;
    for (int i = threadIdx.x; i < 1024; i += 256) {
        int idx = base + i;
        if (idx < n) {
            int d = deg[idx];
            sum += d;
            dinv[idx] = rsqrtf((float)(d + 1));  // +1 self-loop
        }
    }
    sdata[threadIdx.x] = sum;
    __syncthreads();
    for (int s = 128; s > 0; s >>= 1) {
        if (threadIdx.x < s) sdata[threadIdx.x] += sdata[threadIdx.x + s];
        __syncthreads();
    }
    if (threadIdx.x == 0) bsum[blockIdx.x] = sdata[0];
}

// ---------------- W -> MFMA B-fragment layout (device body) ------------------
template <int FOUT, int CT>
__device__ void wconv_body(const float* __restrict__ W, unsigned short* __restrict__ wf) {
    for (int idx = threadIdx.x; idx < CT * 2 * 64 * 8; idx += 256) {
        int j = idx & 7;
        int lane = (idx >> 3) & 63;
        int kh = (idx >> 9) & 1;
        int ct = idx >> 10;
        int k = kh * 32 + ((lane >> 4) * 8) + j;
        int col = ct * 16 + (lane & 15);
        float v = (col < FOUT) ? W[k * FOUT + col] : 0.0f;
        wf[idx] = (unsigned short)bf16rne(v);
    }
}

// ---------------- scan pass 2 (1 block) + wconv x3 (blocks 1..3) -------------
__global__ void scan2_wconv_kernel(int* __restrict__ bsum, int nb,
                                   const float* __restrict__ W0, const float* __restrict__ W1,
                                   const float* __restrict__ W2,
                                   unsigned short* __restrict__ wf0, unsigned short* __restrict__ wf1,
                                   unsigned short* __restrict__ wf2) {
    if (blockIdx.x == 1) { wconv_body<64, 4>(W0, wf0); return; }
    if (blockIdx.x == 2) { wconv_body<64, 4>(W1, wf1); return; }
    if (blockIdx.x == 3) { wconv_body<40, 3>(W2, wf2); return; }
    __shared__ int sdata[256];
    int v = (threadIdx.x < nb) ? bsum[threadIdx.x] : 0;
    sdata[threadIdx.x] = v;
    __syncthreads();
    for (int off = 1; off < 256; off <<= 1) {
        int t = (threadIdx.x >= off) ? sdata[threadIdx.x - off] : 0;
        __syncthreads();
        sdata[threadIdx.x] += t;
        __syncthreads();
    }
    if (threadIdx.x < nb) bsum[threadIdx.x] = sdata[threadIdx.x] - v;  // exclusive
}

__global__ void scan3_kernel(const int* __restrict__ deg, const int* __restrict__ bsum,
                             int* __restrict__ rowptr, int n) {
    __shared__ int ssum[256];
    int base = blockIdx.x * 1024 + threadIdx.x * 4;
    int v[4];
    int s = 0;
#pragma unroll
    for (int k = 0; k < 4; ++k) {
        int idx = base + k;
        v[k] = (idx < n) ? deg[idx] : 0;
        s += v[k];
    }
    ssum[threadIdx.x] = s;
    __syncthreads();
    for (int off = 1; off < 256; off <<= 1) {
        int t = (threadIdx.x >= off) ? ssum[threadIdx.x - off] : 0;
        __syncthreads();
        ssum[threadIdx.x] += t;
        __syncthreads();
    }
    int ex = (threadIdx.x > 0 ? ssum[threadIdx.x - 1] : 0) + bsum[blockIdx.x];
#pragma unroll
    for (int k = 0; k < 4; ++k) {
        int idx = base + k;
        if (idx < n) rowptr[idx] = ex;
        ex += v[k];
    }
}

// ---------------- MFMA dense-transform device body (one 16-row tile) ---------
// hs = dinv * (in @ W) as bf16 [n][FOUT] rows. IN_MODE 0 = fp32, 1 = bf16.
template <int FOUT, int CT, int IN_MODE>
__device__ void gemm_body(int tile, const void* __restrict__ in_,
                          const unsigned short* __restrict__ wf,
                          const float* __restrict__ dinv, unsigned int* __restrict__ hs32,
                          int n, int lane) {
    bf16x8 bfrag[CT][2];
#pragma unroll
    for (int ct = 0; ct < CT; ++ct)
#pragma unroll
        for (int kh = 0; kh < 2; ++kh)
            bfrag[ct][kh] = *(const bf16x8*)(wf + ((size_t)(ct * 2 + kh) * 64 + lane) * 8);

    int rloc = lane & 15;   // A row within tile
    int koct = lane >> 4;   // k octet 0..3
    int rbase = tile * 16;
    int r = rbase + rloc;
    int rc = (r < n) ? r : (n - 1);
    bf16x8 af0, af1;
    if (IN_MODE == 1) {
        const unsigned short* inb = (const unsigned short*)in_;
        af0 = *(const bf16x8*)(inb + (size_t)rc * 64 + koct * 8);       // k 0..31
        af1 = *(const bf16x8*)(inb + (size_t)rc * 64 + 32 + koct * 8);  // k 32..63
    } else {
        const float* inf = (const float*)in_;
        const float* ap = inf + (size_t)rc * 64 + koct * 8;
        float av[16];
        *(float4*)(av + 0)  = *(const float4*)(ap + 0);
        *(float4*)(av + 4)  = *(const float4*)(ap + 4);
        *(float4*)(av + 8)  = *(const float4*)(ap + 32);
        *(float4*)(av + 12) = *(const float4*)(ap + 36);
#pragma unroll
        for (int j = 0; j < 8; ++j) {
            af0[j] = (short)bf16rne(av[j]);
            af1[j] = (short)bf16rne(av[8 + j]);
        }
    }
    // dinv for the 4 output rows this lane touches (independent of ct)
    float dd[4];
#pragma unroll
    for (int reg = 0; reg < 4; ++reg) {
        int row = rbase + koct * 4 + reg;
        dd[reg] = dinv[(row < n) ? row : (n - 1)];
    }
#pragma unroll
    for (int ct = 0; ct < CT; ++ct) {
        f32x4 acc = {0.0f, 0.0f, 0.0f, 0.0f};
        acc = __builtin_amdgcn_mfma_f32_16x16x32_bf16(af0, bfrag[ct][0], acc, 0, 0, 0);
        acc = __builtin_amdgcn_mfma_f32_16x16x32_bf16(af1, bfrag[ct][1], acc, 0, 0, 0);
        int col = ct * 16 + rloc;  // D col = lane&15
#pragma unroll
        for (int reg = 0; reg < 4; ++reg) {
            int row = rbase + koct * 4 + reg;  // D row = (lane>>4)*4+reg
            float v = acc[reg] * dd[reg];
            float po = __shfl_xor(v, 1, 64);   // partner column (lane^1)
            if (row < n && ((lane & 1) == 0) && col < FOUT) {
                hs32[(size_t)row * (FOUT / 2) + (col >> 1)] = bf16rne(v) | (bf16rne(po) << 16);
            }
        }
    }
}

template <int FOUT, int CT, int IN_MODE>
__global__ void gemm_mfma_kernel(const void* __restrict__ in_, const unsigned short* __restrict__ wf,
                                 const float* __restrict__ dinv, unsigned int* __restrict__ hs32,
                                 int n) {
    int lane = threadIdx.x & 63;
    int tile = blockIdx.x * 4 + (threadIdx.x >> 6);
    if (tile * 16 < n)
        gemm_body<FOUT, CT, IN_MODE>(tile, in_, wf, dinv, hs32, n, lane);
}

// ---------------- fused CSR fill + layer-0 gemm ------------------------------
__global__ void fill_gemm0_kernel(const int* __restrict__ src, const int* __restrict__ dst,
                                  const int* __restrict__ pos, const int* __restrict__ rowptr,
                                  int* __restrict__ adj, int E, int nfb,
                                  const float* __restrict__ x, const unsigned short* __restrict__ wf0,
                                  const float* __restrict__ dinv, unsigned int* __restrict__ hs,
                                  int n) {
    if ((int)blockIdx.x < nfb) {
        int e = blockIdx.x * blockDim.x + threadIdx.x;
        if (e < E) adj[rowptr[dst[e]] + pos[e]] = src[e];
    } else {
        int lane = threadIdx.x & 63;
        int tile = (blockIdx.x - nfb) * 4 + (threadIdx.x >> 6);
        if (tile * 16 < n)
            gemm_body<64, 4, 0>(tile, x, wf0, dinv, hs, n, lane);
    }
}

// ---------------- gather full-row pass: [n][64] bf16 rows --------------------
// 16-lane quarter per node, split into two 8-lane subgroups (g = 0/1) that
// each handle one edge per step (2 edges in flight per quarter).
// Lane j (0..7) of a subgroup loads uint4 = u32 features 4j..4j+3 (16B).
// sum = hs[v] + sum_{e: dst=v} hs[src_e]
// OMODE 0: outA = bf16(relu(dinv[v]*sum + b))
// OMODE 1: same + outB = bf16(dinv[v] * relu(...))   (pre-scaled for next agg)
// OMODE 2: outA = bf16(sum)                           (raw; scale folded later)
template <int OMODE, int TAG>
__global__ void gather_full_kernel(const int* __restrict__ rowptr, const int* __restrict__ deg,
                                   const int* __restrict__ adj, const uint4* __restrict__ h4,
                                   const float* __restrict__ dinv, const float* __restrict__ b,
                                   uint4* __restrict__ outA, uint4* __restrict__ outB, int n) {
    int lane = threadIdx.x & 63;
    int wid = threadIdx.x >> 6;
    int i = lane & 15;           // adj slot within quarter
    int qbase = lane & ~15;      // first lane of this quarter
    int g = (lane >> 3) & 1;     // edge subgroup within quarter
    int j = lane & 7;            // uint4 slot within row
    int node = blockIdx.x * 16 + wid * 4 + (lane >> 4);
    if (node >= n) return;
    float a0 = 0.f, a1 = 0.f, a2 = 0.f, a3 = 0.f, a4 = 0.f, a5 = 0.f, a6 = 0.f, a7 = 0.f;
#define ACC_V(v)                                              \
    do {                                                      \
        a0 += bf2f((v).x); a1 += bf2f_hi((v).x);              \
        a2 += bf2f((v).y); a3 += bf2f_hi((v).y);              \
        a4 += bf2f((v).z); a5 += bf2f_hi((v).z);              \
        a6 += bf2f((v).w); a7 += bf2f_hi((v).w);              \
    } while (0)
    if (g == 0) {  // self term counted once
        uint4 v = h4[(size_t)node * 8 + j];
        ACC_V(v);
    }
    int r0 = rowptr[node];
    int cnt = deg[node];
    int nf = cnt & ~15;
    for (int j0 = 0; j0 < nf; j0 += 16) {
        int sv = adj[r0 + j0 + i];  // coalesced: 16 adj entries per quarter
#pragma unroll
        for (int t = 0; t < 8; ++t) {
            int s = __shfl(sv, qbase + 2 * t + g, 64);  // subgroup's edge
            uint4 v = h4[(size_t)s * 8 + j];
            ACC_V(v);
        }
    }
    int rem = cnt - nf;  // 0..15
    if (rem) {
        int sv = adj[r0 + nf + i];  // adj padded by 64 ints -> safe
#pragma unroll
        for (int tb = 0; tb < 8; tb += 2) {
            if (2 * tb < rem) {            // quarter-uniform chunk guard
#pragma unroll
                for (int t = tb; t < tb + 2; ++t) {
                    int e = 2 * t + g;
                    if (e < rem) {         // subgroup-uniform
                        int s = __shfl(sv, qbase + e, 64);
                        uint4 v = h4[(size_t)s * 8 + j];
                        ACC_V(v);
                    }
                }
            }
        }
    }
#undef ACC_V
    // merge the two 8-lane subgroups
    a0 += __shfl_xor(a0, 8, 64); a1 += __shfl_xor(a1, 8, 64);
    a2 += __shfl_xor(a2, 8, 64); a3 += __shfl_xor(a3, 8, 64);
    a4 += __shfl_xor(a4, 8, 64); a5 += __shfl_xor(a5, 8, 64);
    a6 += __shfl_xor(a6, 8, 64); a7 += __shfl_xor(a7, 8, 64);
    if (g != 0) return;
    if (OMODE == 2) {
        uint4 o;
        o.x = bf16rne(a0) | (bf16rne(a1) << 16);
        o.y = bf16rne(a2) | (bf16rne(a3) << 16);
        o.z = bf16rne(a4) | (bf16rne(a5) << 16);
        o.w = bf16rne(a6) | (bf16rne(a7) << 16);
        outA[(size_t)node * 8 + j] = o;
    } else {
        float dd = dinv[node];
        float4 bv0 = ((const float4*)b)[2 * j];
        float4 bv1 = ((const float4*)b)[2 * j + 1];
        float t0 = fmaxf(fmaf(a0, dd, bv0.x), 0.0f);
        float t1 = fmaxf(fmaf(a1, dd, bv0.y), 0.0f);
        float t2 = fmaxf(fmaf(a2, dd, bv0.z), 0.0f);
        float t3 = fmaxf(fmaf(a3, dd, bv0.w), 0.0f);
        float t4 = fmaxf(fmaf(a4, dd, bv1.x), 0.0f);
        float t5 = fmaxf(fmaf(a5, dd, bv1.y), 0.0f);
        float t6 = fmaxf(fmaf(a6, dd, bv1.z), 0.0f);
        float t7 = fmaxf(fmaf(a7, dd, bv1.w), 0.0f);
        uint4 o;
        o.x = bf16rne(t0) | (bf16rne(t1) << 16);
        o.y = bf16rne(t2) | (bf16rne(t3) << 16);
        o.z = bf16rne(t4) | (bf16rne(t5) << 16);
        o.w = bf16rne(t6) | (bf16rne(t7) << 16);
        outA[(size_t)node * 8 + j] = o;
        if (OMODE == 1) {
            uint4 ob;
            ob.x = bf16rne(t0 * dd) | (bf16rne(t1 * dd) << 16);
            ob.y = bf16rne(t2 * dd) | (bf16rne(t3 * dd) << 16);
            ob.z = bf16rne(t4 * dd) | (bf16rne(t5 * dd) << 16);
            ob.w = bf16rne(t6 * dd) | (bf16rne(t7 * dd) << 16);
            outB[(size_t)node * 8 + j] = ob;
        }
    }
}

// ---------------- final GEMM40 + dinv + bias + fused log_softmax -------------
// in = aggregated rows [n][64] bf16; out = log_softmax(dinv[row]*(agg@W2) + b2)
__global__ void gemm40_lsm_kernel(const unsigned int* __restrict__ in_,
                                  const unsigned short* __restrict__ wf,
                                  const float* __restrict__ dinv, const float* __restrict__ b,
                                  float* __restrict__ out, int n) {
    const int CT = 3;
    int lane = threadIdx.x & 63;
    int tile = blockIdx.x * 4 + (threadIdx.x >> 6);
    if (tile * 16 >= n) return;
    bf16x8 bfrag[CT][2];
#pragma unroll
    for (int ct = 0; ct < CT; ++ct)
#pragma unroll
        for (int kh = 0; kh < 2; ++kh)
            bfrag[ct][kh] = *(const bf16x8*)(wf + ((size_t)(ct * 2 + kh) * 64 + lane) * 8);

    int rloc = lane & 15;
    int koct = lane >> 4;
    float bc[CT];
#pragma unroll
    for (int ct = 0; ct < CT; ++ct) {
        int col = ct * 16 + rloc;
        bc[ct] = (col < 40) ? b[col] : -INFINITY;
    }
    const unsigned short* inb = (const unsigned short*)in_;
    int rbase = tile * 16;
    int r = rbase + rloc;
    int rc = (r < n) ? r : (n - 1);
    bf16x8 af0 = *(const bf16x8*)(inb + (size_t)rc * 64 + koct * 8);
    bf16x8 af1 = *(const bf16x8*)(inb + (size_t)rc * 64 + 32 + koct * 8);
    f32x4 acc[CT];
#pragma unroll
    for (int ct = 0; ct < CT; ++ct) {
        f32x4 a = {0.0f, 0.0f, 0.0f, 0.0f};
        a = __builtin_amdgcn_mfma_f32_16x16x32_bf16(af0, bfrag[ct][0], a, 0, 0, 0);
        a = __builtin_amdgcn_mfma_f32_16x16x32_bf16(af1, bfrag[ct][1], a, 0, 0, 0);
        acc[ct] = a;
    }
#pragma unroll
    for (int reg = 0; reg < 4; ++reg) {
        int row = rbase + koct * 4 + reg;
        float dd = dinv[(row < n) ? row : (n - 1)];
        float v0 = fmaf(acc[0][reg], dd, bc[0]);
        float v1 = fmaf(acc[1][reg], dd, bc[1]);
        float v2 = fmaf(acc[2][reg], dd, bc[2]);
        float m = fmaxf(fmaxf(v0, v1), v2);
#pragma unroll
        for (int off = 8; off >= 1; off >>= 1) m = fmaxf(m, __shfl_xor(m, off, 16));
        float es = expf(v0 - m) + expf(v1 - m) + ((v2 == -INFINITY) ? 0.0f : expf(v2 - m));
#pragma unroll
        for (int off = 8; off >= 1; off >>= 1) es += __shfl_xor(es, off, 16);
        float ls = m + logf(es);
        if (row < n) {
            out[(size_t)row * 40 + rloc] = v0 - ls;
            out[(size_t)row * 40 + 16 + rloc] = v1 - ls;
            if (rloc < 8) out[(size_t)row * 40 + 32 + rloc] = v2 - ls;
        }
    }
}

extern "C" void kernel_launch(void* const* d_in, const int* in_sizes, int n_in,
                              void* d_out, int out_size, void* d_ws, size_t ws_size,
                              hipStream_t stream) {
    const float* x  = (const float*)d_in[0];
    const int*   ei = (const int*)d_in[1];
    const float* W0 = (const float*)d_in[2];
    const float* b0 = (const float*)d_in[3];
    const float* W1 = (const float*)d_in[4];
    const float* b1 = (const float*)d_in[5];
    const float* W2 = (const float*)d_in[6];
    const float* b2 = (const float*)d_in[7];
    float* out = (float*)d_out;

    const int H   = in_sizes[3];            // 64
    const int FIN = in_sizes[2] / H;        // 64
    const int n   = in_sizes[0] / FIN;      // 50000
    const int E   = in_sizes[1] / 2;        // 800000
    (void)FIN;

    const int* srcp = ei;
    const int* dstp = ei + E;

    char* ws = (char*)d_ws;
    size_t off = 0;
    int*   deg    = (int*)(ws + off);   off += ws_align((size_t)n * 4);
    int*   rowptr = (int*)(ws + off);   off += ws_align((size_t)n * 4);
    int*   bsum   = (int*)(ws + off);   off += ws_align(256 * 4);
    float* dinv   = (float*)(ws + off); off += ws_align((size_t)n * 4);
    int*   pos    = (int*)(ws + off);   off += ws_align((size_t)E * 4);
    int*   adj    = (int*)(ws + off);   off += ws_align((size_t)(E + 64) * 4);  // +64 pad for tail reads
    unsigned int* hs    = (unsigned int*)(ws + off); off += ws_align((size_t)n * H * 2);  // [n][64] bf16 rows
    unsigned int* actB  = (unsigned int*)(ws + off); off += ws_align((size_t)n * H * 2);
    unsigned int* actBs = (unsigned int*)(ws + off); off += ws_align((size_t)n * H * 2);
    unsigned short* wf0 = (unsigned short*)(ws + off); off += ws_align(4 * 2 * 64 * 8 * 2);
    unsigned short* wf1 = (unsigned short*)(ws + off); off += ws_align(4 * 2 * 64 * 8 * 2);
    unsigned short* wf2 = (unsigned short*)(ws + off); off += ws_align(3 * 2 * 64 * 8 * 2);

    // CSR build
    zero_kernel<<<(n + 255) / 256, 256, 0, stream>>>(deg, n);
    deg_pos_kernel<<<(E + 255) / 256, 256, 0, stream>>>(dstp, E, deg, pos);
    int nscan = (n + 1023) / 1024;  // 49
    scan1_dinv_kernel<<<nscan, 256, 0, stream>>>(deg, bsum, dinv, n);
    scan2_wconv_kernel<<<4, 256, 0, stream>>>(bsum, nscan, W0, W1, W2, wf0, wf1, wf2);
    scan3_kernel<<<nscan, 256, 0, stream>>>(deg, bsum, rowptr, n);

    int tiles = (n + 15) / 16;                 // 3125
    int gemm_grid = (tiles + 3) / 4;           // 782 blocks, 1 tile/wave
    int fill_grid = (E + 255) / 256;           // 3125
    int node_grid = (n + 15) / 16;             // 16 nodes/block

    // fused: CSR fill + layer-0 gemm (independent work, one launch)
    fill_gemm0_kernel<<<fill_grid + gemm_grid, 256, 0, stream>>>(
        srcp, dstp, pos, rowptr, adj, E, fill_grid, x, wf0, dinv, hs, n);

    // layer 0 gather -> actB (relu bf16)
    gather_full_kernel<0, 0><<<node_grid, 256, 0, stream>>>(rowptr, deg, adj, (const uint4*)hs, dinv, b0, (uint4*)actB, nullptr, n);
    // layer 1: gemm -> hs ; gather -> actB + actBs (dinv-prescaled)
    gemm_mfma_kernel<64, 4, 1><<<gemm_grid, 256, 0, stream>>>(actB, wf1, dinv, hs, n);
    gather_full_kernel<1, 1><<<node_grid, 256, 0, stream>>>(rowptr, deg, adj, (const uint4*)hs, dinv, b1, (uint4*)actB, (uint4*)actBs, n);
    // layer 2 (commuted): aggregate actBs -> hs (raw sums) ; gemm40 + lsm -> out
    gather_full_kernel<2, 2><<<node_grid, 256, 0, stream>>>(rowptr, deg, adj, (const uint4*)actBs, nullptr, nullptr, (uint4*)hs, nullptr, n);
    gemm40_lsm_kernel<<<gemm_grid, 256, 0, stream>>>(hs, wf2, dinv, b2, out, n);
}

// Round 14
// 145.825 us; speedup vs baseline: 1.4804x; 1.0536x over previous
//
#include <hip/hip_runtime.h>
#include <math.h>

static inline size_t ws_align(size_t x) { return (x + 255) & ~size_t(255); }

typedef float f32x4 __attribute__((ext_vector_type(4)));
typedef short bf16x8 __attribute__((ext_vector_type(8)));

__device__ inline unsigned int bf16rne(float f) {
    unsigned int u = __float_as_uint(f);
    u += 0x7FFFu + ((u >> 16) & 1u);
    return u >> 16;
}
__device__ inline float bf2f(unsigned int u) {  // low 16 bits = bf16
    return __uint_as_float(u << 16);
}
__device__ inline float bf2f_hi(unsigned int u) {  // high 16 bits
    return __uint_as_float(u & 0xFFFF0000u);
}

// ---------------- zero deg ----------------
__global__ void zero_kernel(int* __restrict__ p, int n) {
    int i = blockIdx.x * blockDim.x + threadIdx.x;
    if (i < n) p[i] = 0;
}

// ---------------- degree histogram + per-edge slot ----------------
__global__ void deg_pos_kernel(const int* __restrict__ dst, int E,
                               int* __restrict__ deg, int* __restrict__ pos) {
    int e = blockIdx.x * blockDim.x + threadIdx.x;
    if (e < E) pos[e] = atomicAdd(&deg[dst[e]], 1);
}

// ---------------- W -> MFMA B-fragment layout (device body) ------------------
template <int FOUT, int CT>
__device__ void wconv_body(const float* __restrict__ W, unsigned short* __restrict__ wf) {
    for (int idx = threadIdx.x; idx < CT * 2 * 64 * 8; idx += 256) {
        int j = idx & 7;
        int lane = (idx >> 3) & 63;
        int kh = (idx >> 9) & 1;
        int ct = idx >> 10;
        int k = kh * 32 + ((lane >> 4) * 8) + j;
        int col = ct * 16 + (lane & 15);
        float v = (col < FOUT) ? W[k * FOUT + col] : 0.0f;
        wf[idx] = (unsigned short)bf16rne(v);
    }
}

// ---------------- scan pass 1 (block sums) + dinv + wconv x3 -----------------
__global__ void scan1_dinv_wconv_kernel(const int* __restrict__ deg, int* __restrict__ bsum,
                                        float* __restrict__ dinv, int n, int nscan,
                                        const float* __restrict__ W0, const float* __restrict__ W1,
                                        const float* __restrict__ W2,
                                        unsigned short* __restrict__ wf0, unsigned short* __restrict__ wf1,
                                        unsigned short* __restrict__ wf2) {
    if ((int)blockIdx.x >= nscan) {
        int wb = blockIdx.x - nscan;
        if (wb == 0) { wconv_body<64, 4>(W0, wf0); }
        else if (wb == 1) { wconv_body<64, 4>(W1, wf1); }
        else { wconv_body<40, 3>(W2, wf2); }
        return;
    }
    __shared__ int sdata[256];
    int base = blockIdx.x * 1024;
    int sum = 0;
    for (int i = threadIdx.x; i < 1024; i += 256) {
        int idx = base + i;
        if (idx < n) {
            int d = deg[idx];
            sum += d;
            dinv[idx] = rsqrtf((float)(d + 1));  // +1 self-loop
        }
    }
    sdata[threadIdx.x] = sum;
    __syncthreads();
    for (int s = 128; s > 0; s >>= 1) {
        if (threadIdx.x < s) sdata[threadIdx.x] += sdata[threadIdx.x + s];
        __syncthreads();
    }
    if (threadIdx.x == 0) bsum[blockIdx.x] = sdata[0];
}

// ---------------- scan pass 3: self-computed block offset + local scan -------
__global__ void scan3_kernel(const int* __restrict__ deg, const int* __restrict__ bsum, int nb,
                             int* __restrict__ rowptr, int n) {
    __shared__ int ssum[256];
    __shared__ int blockoff_s;
    // block offset = sum of bsum[0 .. blockIdx) (nb <= 64)
    if (threadIdx.x < 64) {
        int t = threadIdx.x;
        int v = (t < nb && t < (int)blockIdx.x) ? bsum[t] : 0;
#pragma unroll
        for (int off = 32; off >= 1; off >>= 1) v += __shfl_xor(v, off, 64);
        if (t == 0) blockoff_s = v;
    }
    int base = blockIdx.x * 1024 + threadIdx.x * 4;
    int v[4];
    int s = 0;
#pragma unroll
    for (int k = 0; k < 4; ++k) {
        int idx = base + k;
        v[k] = (idx < n) ? deg[idx] : 0;
        s += v[k];
    }
    ssum[threadIdx.x] = s;
    __syncthreads();
    for (int off = 1; off < 256; off <<= 1) {
        int t = (threadIdx.x >= off) ? ssum[threadIdx.x - off] : 0;
        __syncthreads();
        ssum[threadIdx.x] += t;
        __syncthreads();
    }
    int ex = (threadIdx.x > 0 ? ssum[threadIdx.x - 1] : 0) + blockoff_s;
#pragma unroll
    for (int k = 0; k < 4; ++k) {
        int idx = base + k;
        if (idx < n) rowptr[idx] = ex;
        ex += v[k];
    }
}

// ---------------- MFMA dense-transform device body (one 16-row tile) ---------
// hs = dinv * (in @ W) as bf16 [n][FOUT] rows. IN_MODE 0 = fp32, 1 = bf16.
template <int FOUT, int CT, int IN_MODE>
__device__ void gemm_body(int tile, const void* __restrict__ in_,
                          const unsigned short* __restrict__ wf,
                          const float* __restrict__ dinv, unsigned int* __restrict__ hs32,
                          int n, int lane) {
    bf16x8 bfrag[CT][2];
#pragma unroll
    for (int ct = 0; ct < CT; ++ct)
#pragma unroll
        for (int kh = 0; kh < 2; ++kh)
            bfrag[ct][kh] = *(const bf16x8*)(wf + ((size_t)(ct * 2 + kh) * 64 + lane) * 8);

    int rloc = lane & 15;   // A row within tile
    int koct = lane >> 4;   // k octet 0..3
    int rbase = tile * 16;
    int r = rbase + rloc;
    int rc = (r < n) ? r : (n - 1);
    bf16x8 af0, af1;
    if (IN_MODE == 1) {
        const unsigned short* inb = (const unsigned short*)in_;
        af0 = *(const bf16x8*)(inb + (size_t)rc * 64 + koct * 8);       // k 0..31
        af1 = *(const bf16x8*)(inb + (size_t)rc * 64 + 32 + koct * 8);  // k 32..63
    } else {
        const float* inf = (const float*)in_;
        const float* ap = inf + (size_t)rc * 64 + koct * 8;
        float av[16];
        *(float4*)(av + 0)  = *(const float4*)(ap + 0);
        *(float4*)(av + 4)  = *(const float4*)(ap + 4);
        *(float4*)(av + 8)  = *(const float4*)(ap + 32);
        *(float4*)(av + 12) = *(const float4*)(ap + 36);
#pragma unroll
        for (int j = 0; j < 8; ++j) {
            af0[j] = (short)bf16rne(av[j]);
            af1[j] = (short)bf16rne(av[8 + j]);
        }
    }
    float dd[4];
#pragma unroll
    for (int reg = 0; reg < 4; ++reg) {
        int row = rbase + koct * 4 + reg;
        dd[reg] = dinv[(row < n) ? row : (n - 1)];
    }
#pragma unroll
    for (int ct = 0; ct < CT; ++ct) {
        f32x4 acc = {0.0f, 0.0f, 0.0f, 0.0f};
        acc = __builtin_amdgcn_mfma_f32_16x16x32_bf16(af0, bfrag[ct][0], acc, 0, 0, 0);
        acc = __builtin_amdgcn_mfma_f32_16x16x32_bf16(af1, bfrag[ct][1], acc, 0, 0, 0);
        int col = ct * 16 + rloc;  // D col = lane&15
#pragma unroll
        for (int reg = 0; reg < 4; ++reg) {
            int row = rbase + koct * 4 + reg;  // D row = (lane>>4)*4+reg
            float v = acc[reg] * dd[reg];
            float po = __shfl_xor(v, 1, 64);   // partner column (lane^1)
            if (row < n && ((lane & 1) == 0) && col < FOUT) {
                hs32[(size_t)row * (FOUT / 2) + (col >> 1)] = bf16rne(v) | (bf16rne(po) << 16);
            }
        }
    }
}

template <int FOUT, int CT, int IN_MODE>
__global__ void gemm_mfma_kernel(const void* __restrict__ in_, const unsigned short* __restrict__ wf,
                                 const float* __restrict__ dinv, unsigned int* __restrict__ hs32,
                                 int n) {
    int lane = threadIdx.x & 63;
    int tile = blockIdx.x * 4 + (threadIdx.x >> 6);
    if (tile * 16 < n)
        gemm_body<FOUT, CT, IN_MODE>(tile, in_, wf, dinv, hs32, n, lane);
}

// ---------------- fused CSR fill + layer-0 gemm ------------------------------
__global__ void fill_gemm0_kernel(const int* __restrict__ src, const int* __restrict__ dst,
                                  const int* __restrict__ pos, const int* __restrict__ rowptr,
                                  int* __restrict__ adj, int E, int nfb,
                                  const float* __restrict__ x, const unsigned short* __restrict__ wf0,
                                  const float* __restrict__ dinv, unsigned int* __restrict__ hs,
                                  int n) {
    if ((int)blockIdx.x < nfb) {
        int e = blockIdx.x * blockDim.x + threadIdx.x;
        if (e < E) adj[rowptr[dst[e]] + pos[e]] = src[e];
    } else {
        int lane = threadIdx.x & 63;
        int tile = (blockIdx.x - nfb) * 4 + (threadIdx.x >> 6);
        if (tile * 16 < n)
            gemm_body<64, 4, 0>(tile, x, wf0, dinv, hs, n, lane);
    }
}

// ---------------- gather full-row pass: [n][64] bf16 rows --------------------
// 32 lanes per node (2 nodes/wave), 4 subgroups of 8 lanes; each subgroup
// handles one edge per step (4 edges in flight per node).
// Lane j (0..7) of a subgroup loads uint4 = u32 features 4j..4j+3 (16B).
// sum = hs[v] + sum_{e: dst=v} hs[src_e]
// OMODE 0: outA = bf16(relu(dinv[v]*sum + b))
// OMODE 1: same + outB = bf16(dinv[v] * relu(...))   (pre-scaled for next agg)
// OMODE 2: outA = bf16(sum)                           (raw; scale folded later)
template <int OMODE, int TAG>
__global__ void gather_full_kernel(const int* __restrict__ rowptr, const int* __restrict__ deg,
                                   const int* __restrict__ adj, const uint4* __restrict__ h4,
                                   const float* __restrict__ dinv, const float* __restrict__ b,
                                   uint4* __restrict__ outA, uint4* __restrict__ outB, int n) {
    int lane = threadIdx.x & 63;
    int wid = threadIdx.x >> 6;
    int half = lane >> 5;        // node within wave
    int L = lane & 31;           // lane within node group
    int i = L & 15;              // adj slot
    int g = (L >> 3) & 3;        // subgroup 0..3
    int j = lane & 7;            // uint4 slot within row
    int gbase = lane & ~31;      // first lane of node group
    int node = blockIdx.x * 8 + wid * 2 + half;
    if (node >= n) return;
    float a0 = 0.f, a1 = 0.f, a2 = 0.f, a3 = 0.f, a4 = 0.f, a5 = 0.f, a6 = 0.f, a7 = 0.f;
#define ACC_V(v)                                              \
    do {                                                      \
        a0 += bf2f((v).x); a1 += bf2f_hi((v).x);              \
        a2 += bf2f((v).y); a3 += bf2f_hi((v).y);              \
        a4 += bf2f((v).z); a5 += bf2f_hi((v).z);              \
        a6 += bf2f((v).w); a7 += bf2f_hi((v).w);              \
    } while (0)
    if (g == 0) {  // self term counted once
        uint4 v = h4[(size_t)node * 8 + j];
        ACC_V(v);
    }
    int r0 = rowptr[node];
    int cnt = deg[node];
    int nf = cnt & ~15;
    for (int j0 = 0; j0 < nf; j0 += 16) {
        int sv = adj[r0 + j0 + i];  // 16 adj entries per node group
#pragma unroll
        for (int t = 0; t < 4; ++t) {
            int s = __shfl(sv, gbase + 4 * t + g, 64);  // subgroup's edge
            uint4 v = h4[(size_t)s * 8 + j];
            ACC_V(v);
        }
    }
    int rem = cnt - nf;  // 0..15
    if (rem) {
        int sv = adj[r0 + nf + i];  // adj padded by 64 ints -> safe
#pragma unroll
        for (int t = 0; t < 4; ++t) {
            int e = 4 * t + g;
            if (e < rem) {          // subgroup-uniform
                int s = __shfl(sv, gbase + e, 64);
                uint4 v = h4[(size_t)s * 8 + j];
                ACC_V(v);
            }
        }
    }
#undef ACC_V
    // merge the four 8-lane subgroups (within the 32-lane node group)
    a0 += __shfl_xor(a0, 8, 64); a1 += __shfl_xor(a1, 8, 64);
    a2 += __shfl_xor(a2, 8, 64); a3 += __shfl_xor(a3, 8, 64);
    a4 += __shfl_xor(a4, 8, 64); a5 += __shfl_xor(a5, 8, 64);
    a6 += __shfl_xor(a6, 8, 64); a7 += __shfl_xor(a7, 8, 64);
    a0 += __shfl_xor(a0, 16, 64); a1 += __shfl_xor(a1, 16, 64);
    a2 += __shfl_xor(a2, 16, 64); a3 += __shfl_xor(a3, 16, 64);
    a4 += __shfl_xor(a4, 16, 64); a5 += __shfl_xor(a5, 16, 64);
    a6 += __shfl_xor(a6, 16, 64); a7 += __shfl_xor(a7, 16, 64);
    if (g != 0) return;
    if (OMODE == 2) {
        uint4 o;
        o.x = bf16rne(a0) | (bf16rne(a1) << 16);
        o.y = bf16rne(a2) | (bf16rne(a3) << 16);
        o.z = bf16rne(a4) | (bf16rne(a5) << 16);
        o.w = bf16rne(a6) | (bf16rne(a7) << 16);
        outA[(size_t)node * 8 + j] = o;
    } else {
        float dd = dinv[node];
        float4 bv0 = ((const float4*)b)[2 * j];
        float4 bv1 = ((const float4*)b)[2 * j + 1];
        float t0 = fmaxf(fmaf(a0, dd, bv0.x), 0.0f);
        float t1 = fmaxf(fmaf(a1, dd, bv0.y), 0.0f);
        float t2 = fmaxf(fmaf(a2, dd, bv0.z), 0.0f);
        float t3 = fmaxf(fmaf(a3, dd, bv0.w), 0.0f);
        float t4 = fmaxf(fmaf(a4, dd, bv1.x), 0.0f);
        float t5 = fmaxf(fmaf(a5, dd, bv1.y), 0.0f);
        float t6 = fmaxf(fmaf(a6, dd, bv1.z), 0.0f);
        float t7 = fmaxf(fmaf(a7, dd, bv1.w), 0.0f);
        uint4 o;
        o.x = bf16rne(t0) | (bf16rne(t1) << 16);
        o.y = bf16rne(t2) | (bf16rne(t3) << 16);
        o.z = bf16rne(t4) | (bf16rne(t5) << 16);
        o.w = bf16rne(t6) | (bf16rne(t7) << 16);
        outA[(size_t)node * 8 + j] = o;
        if (OMODE == 1) {
            uint4 ob;
            ob.x = bf16rne(t0 * dd) | (bf16rne(t1 * dd) << 16);
            ob.y = bf16rne(t2 * dd) | (bf16rne(t3 * dd) << 16);
            ob.z = bf16rne(t4 * dd) | (bf16rne(t5 * dd) << 16);
            ob.w = bf16rne(t6 * dd) | (bf16rne(t7 * dd) << 16);
            outB[(size_t)node * 8 + j] = ob;
        }
    }
}

// ---------------- final GEMM40 + dinv + bias + fused log_softmax -------------
__global__ void gemm40_lsm_kernel(const unsigned int* __restrict__ in_,
                                  const unsigned short* __restrict__ wf,
                                  const float* __restrict__ dinv, const float* __restrict__ b,
                                  float* __restrict__ out, int n) {
    const int CT = 3;
    int lane = threadIdx.x & 63;
    int tile = blockIdx.x * 4 + (threadIdx.x >> 6);
    if (tile * 16 >= n) return;
    bf16x8 bfrag[CT][2];
#pragma unroll
    for (int ct = 0; ct < CT; ++ct)
#pragma unroll
        for (int kh = 0; kh < 2; ++kh)
            bfrag[ct][kh] = *(const bf16x8*)(wf + ((size_t)(ct * 2 + kh) * 64 + lane) * 8);

    int rloc = lane & 15;
    int koct = lane >> 4;
    float bc[CT];
#pragma unroll
    for (int ct = 0; ct < CT; ++ct) {
        int col = ct * 16 + rloc;
        bc[ct] = (col < 40) ? b[col] : -INFINITY;
    }
    const unsigned short* inb = (const unsigned short*)in_;
    int rbase = tile * 16;
    int r = rbase + rloc;
    int rc = (r < n) ? r : (n - 1);
    bf16x8 af0 = *(const bf16x8*)(inb + (size_t)rc * 64 + koct * 8);
    bf16x8 af1 = *(const bf16x8*)(inb + (size_t)rc * 64 + 32 + koct * 8);
    f32x4 acc[CT];
#pragma unroll
    for (int ct = 0; ct < CT; ++ct) {
        f32x4 a = {0.0f, 0.0f, 0.0f, 0.0f};
        a = __builtin_amdgcn_mfma_f32_16x16x32_bf16(af0, bfrag[ct][0], a, 0, 0, 0);
        a = __builtin_amdgcn_mfma_f32_16x16x32_bf16(af1, bfrag[ct][1], a, 0, 0, 0);
        acc[ct] = a;
    }
#pragma unroll
    for (int reg = 0; reg < 4; ++reg) {
        int row = rbase + koct * 4 + reg;
        float dd = dinv[(row < n) ? row : (n - 1)];
        float v0 = fmaf(acc[0][reg], dd, bc[0]);
        float v1 = fmaf(acc[1][reg], dd, bc[1]);
        float v2 = fmaf(acc[2][reg], dd, bc[2]);
        float m = fmaxf(fmaxf(v0, v1), v2);
#pragma unroll
        for (int off = 8; off >= 1; off >>= 1) m = fmaxf(m, __shfl_xor(m, off, 16));
        float es = expf(v0 - m) + expf(v1 - m) + ((v2 == -INFINITY) ? 0.0f : expf(v2 - m));
#pragma unroll
        for (int off = 8; off >= 1; off >>= 1) es += __shfl_xor(es, off, 16);
        float ls = m + logf(es);
        if (row < n) {
            out[(size_t)row * 40 + rloc] = v0 - ls;
            out[(size_t)row * 40 + 16 + rloc] = v1 - ls;
            if (rloc < 8) out[(size_t)row * 40 + 32 + rloc] = v2 - ls;
        }
    }
}

extern "C" void kernel_launch(void* const* d_in, const int* in_sizes, int n_in,
                              void* d_out, int out_size, void* d_ws, size_t ws_size,
                              hipStream_t stream) {
    const float* x  = (const float*)d_in[0];
    const int*   ei = (const int*)d_in[1];
    const float* W0 = (const float*)d_in[2];
    const float* b0 = (const float*)d_in[3];
    const float* W1 = (const float*)d_in[4];
    const float* b1 = (const float*)d_in[5];
    const float* W2 = (const float*)d_in[6];
    const float* b2 = (const float*)d_in[7];
    float* out = (float*)d_out;

    const int H   = in_sizes[3];            // 64
    const int FIN = in_sizes[2] / H;        // 64
    const int n   = in_sizes[0] / FIN;      // 50000
    const int E   = in_sizes[1] / 2;        // 800000
    (void)FIN;

    const int* srcp = ei;
    const int* dstp = ei + E;

    char* ws = (char*)d_ws;
    size_t off = 0;
    int*   deg    = (int*)(ws + off);   off += ws_align((size_t)n * 4);
    int*   rowptr = (int*)(ws + off);   off += ws_align((size_t)n * 4);
    int*   bsum   = (int*)(ws + off);   off += ws_align(256 * 4);
    float* dinv   = (float*)(ws + off); off += ws_align((size_t)n * 4);
    int*   pos    = (int*)(ws + off);   off += ws_align((size_t)E * 4);
    int*   adj    = (int*)(ws + off);   off += ws_align((size_t)(E + 64) * 4);  // +64 pad for tail reads
    unsigned int* hs    = (unsigned int*)(ws + off); off += ws_align((size_t)n * H * 2);  // [n][64] bf16 rows
    unsigned int* actB  = (unsigned int*)(ws + off); off += ws_align((size_t)n * H * 2);
    unsigned int* actBs = (unsigned int*)(ws + off); off += ws_align((size_t)n * H * 2);
    unsigned short* wf0 = (unsigned short*)(ws + off); off += ws_align(4 * 2 * 64 * 8 * 2);
    unsigned short* wf1 = (unsigned short*)(ws + off); off += ws_align(4 * 2 * 64 * 8 * 2);
    unsigned short* wf2 = (unsigned short*)(ws + off); off += ws_align(3 * 2 * 64 * 8 * 2);

    // CSR build
    zero_kernel<<<(n + 255) / 256, 256, 0, stream>>>(deg, n);
    deg_pos_kernel<<<(E + 255) / 256, 256, 0, stream>>>(dstp, E, deg, pos);
    int nscan = (n + 1023) / 1024;  // 49
    scan1_dinv_wconv_kernel<<<nscan + 3, 256, 0, stream>>>(deg, bsum, dinv, n, nscan,
                                                           W0, W1, W2, wf0, wf1, wf2);
    scan3_kernel<<<nscan, 256, 0, stream>>>(deg, bsum, nscan, rowptr, n);

    int tiles = (n + 15) / 16;                 // 3125
    int gemm_grid = (tiles + 3) / 4;           // 782 blocks, 1 tile/wave
    int fill_grid = (E + 255) / 256;           // 3125
    int node_grid = (n + 7) / 8;               // 8 nodes/block (32 lanes/node)

    // fused: CSR fill + layer-0 gemm (independent work, one launch)
    fill_gemm0_kernel<<<fill_grid + gemm_grid, 256, 0, stream>>>(
        srcp, dstp, pos, rowptr, adj, E, fill_grid, x, wf0, dinv, hs, n);

    // layer 0 gather -> actB (relu bf16)
    gather_full_kernel<0, 0><<<node_grid, 256, 0, stream>>>(rowptr, deg, adj, (const uint4*)hs, dinv, b0, (uint4*)actB, nullptr, n);
    // layer 1: gemm -> hs ; gather -> actB + actBs (dinv-prescaled)
    gemm_mfma_kernel<64, 4, 1><<<gemm_grid, 256, 0, stream>>>(actB, wf1, dinv, hs, n);
    gather_full_kernel<1, 1><<<node_grid, 256, 0, stream>>>(rowptr, deg, adj, (const uint4*)hs, dinv, b1, (uint4*)actB, (uint4*)actBs, n);
    // layer 2 (commuted): aggregate actBs -> hs (raw sums) ; gemm40 + lsm -> out
    gather_full_kernel<2, 2><<<node_grid, 256, 0, stream>>>(rowptr, deg, adj, (const uint4*)actBs, nullptr, nullptr, (uint4*)hs, nullptr, n);
    gemm40_lsm_kernel<<<gemm_grid, 256, 0, stream>>>(hs, wf2, dinv, b2, out, n);
}